// Round 1
// baseline (235.354 us; speedup 1.0000x reference)
//
#include <hip/hip_runtime.h>
#include <hip/hip_bf16.h>
#include <math.h>

// Problem constants (fixed instance)
#define UQ   1024     // user pairs
#define NUQ  2048     // 2U user nodes
#define MQ   64       // UAV nodes
#define NN   2112     // total nodes
#define HD   256      // hidden
#define NCH  16       // chunks per UAV in edge kernel (128 users each)

typedef __attribute__((ext_vector_type(4))) float f32x4;
typedef __attribute__((ext_vector_type(8))) __bf16 bf16x8;

// ---- workspace layout (bytes, all 256-aligned) ----
#define OFF_HB    0u          // h bf16 [2112][256]              1,081,344
#define OFF_ACAT  1081344u    // Acat bf16 [2112][512] = [agg|h] 2,162,688
#define OFF_PU    3244032u    // P_user f32 [2048][256]          2,097,152
#define OFF_PB    5341184u    // P_uav+b1 f32 [64][256]             65,536
#define OFF_SPR   5406720u    // s'_m f32 [64]                        256
#define OFF_ATT   5406976u    // wqa[256], v[256], const0           2,304
#define OFF_WHHT  5409280u    // user WhhT2 f32 [2][128][512]     524,288
#define OFF_WIHT  5933568u    // uav WihT2 f32 [2][256][512]    1,048,576
#define OFF_MW1   6982144u    // msg_w1 bf16 [256][512]           262,144
#define OFF_MW2   7244288u    // msg_w2 bf16 [256][256]           131,072
#define OFF_UW1   7375360u    // upd_w1 bf16 [256][512]           262,144
#define OFF_UW2   7637504u    // upd_w2 bf16 [256][256]           131,072
#define OFF_CREC  7768576u    // chunk rec f32 [1024][260]      1,064,960
#define OFF_L1B   8833536u    // upd layer1 bf16 [2112][256]    1,081,344
#define OFF_H2    9914880u    // h2 f32 [2112][256]             2,162,688
// total ~12.1 MB

__device__ __forceinline__ float sigm(float v) { return 1.f / (1.f + expf(-v)); }

// =====================================================================
// K0: weight preprocessing (transposes, bf16 casts, attention precompute)
// =====================================================================
__global__ __launch_bounds__(256) void k0_prep(
    const float* __restrict__ ul_whh, const float* __restrict__ uavl_wih,
    const float* __restrict__ msg_w1, const float* __restrict__ msg_w2,
    const float* __restrict__ upd_w1, const float* __restrict__ upd_w2,
    const float* __restrict__ att_w,  const float* __restrict__ att_b,
    const float* __restrict__ wq_w,   const float* __restrict__ wq_b,
    const float* __restrict__ wr_w,   const float* __restrict__ wr_b,
    char* __restrict__ ws)
{
  const int b = blockIdx.x, t = threadIdx.x;
  if (b < 8) {
    // user WhhT2[dir][k][hc*4+g] = ul_whh[dir][(g*128+hc)][k]   (131072 elems)
    float* o = (float*)(ws + OFF_WHHT);
    for (int idx = b * 16384 + t; idx < (b + 1) * 16384; idx += 256) {
      int dir = idx >> 16, rem = idx & 65535;
      int k = rem >> 9, hc4 = rem & 511;
      int hc = hc4 >> 2, g = hc4 & 3;
      o[idx] = ul_whh[dir * 65536 + (g * 128 + hc) * 128 + k];
    }
  } else if (b < 24) {
    // uav WihT2[dir][k][hc*4+g] = uavl_wih[dir][(g*128+hc)][k]  (262144 elems)
    float* o = (float*)(ws + OFF_WIHT);
    const int b2 = b - 8;
    for (int idx = b2 * 16384 + t; idx < (b2 + 1) * 16384; idx += 256) {
      int dir = idx >> 17, rem = idx & 131071;
      int k = rem >> 9, hc4 = rem & 511;
      int hc = hc4 >> 2, g = hc4 & 3;
      o[idx] = uavl_wih[dir * 131072 + (g * 128 + hc) * 256 + k];
    }
  } else if (b < 32) {
    __bf16* o = (__bf16*)(ws + OFF_MW1); const int b2 = b - 24;
    for (int idx = b2 * 16384 + t; idx < (b2 + 1) * 16384; idx += 256) o[idx] = (__bf16)msg_w1[idx];
  } else if (b < 36) {
    __bf16* o = (__bf16*)(ws + OFF_MW2); const int b2 = b - 32;
    for (int idx = b2 * 16384 + t; idx < (b2 + 1) * 16384; idx += 256) o[idx] = (__bf16)msg_w2[idx];
  } else if (b < 44) {
    __bf16* o = (__bf16*)(ws + OFF_UW1); const int b2 = b - 36;
    for (int idx = b2 * 16384 + t; idx < (b2 + 1) * 16384; idx += 256) o[idx] = (__bf16)upd_w1[idx];
  } else if (b < 48) {
    __bf16* o = (__bf16*)(ws + OFF_UW2); const int b2 = b - 44;
    for (int idx = b2 * 16384 + t; idx < (b2 + 1) * 16384; idx += 256) o[idx] = (__bf16)upd_w2[idx];
  } else {
    // attention precompute: wqa = Wq^T att_a ; v = Wr^T att_r ; const0
    float* wqa = (float*)(ws + OFF_ATT);
    float* vv  = wqa + 256;
    float* c0  = wqa + 512;
    float sa = 0.f, sr = 0.f;
    for (int j = 0; j < 256; ++j) {
      sa += att_w[j]       * wq_w[j * 256 + t];
      sr += att_w[256 + j] * wr_w[j * 256 + t];
    }
    wqa[t] = sa; vv[t] = sr;
    __shared__ float red[256];
    red[t] = att_w[t] * wq_b[t] + att_w[256 + t] * wr_b[t];
    __syncthreads();
    for (int s = 128; s > 0; s >>= 1) { if (t < s) red[t] += red[t + s]; __syncthreads(); }
    if (t == 0) c0[0] = red[0] + att_b[0];
  }
}

// =====================================================================
// K1: user BiLSTM (4 users/block) + UAV linear embed; writes h_bf16, Acat
// =====================================================================
__global__ __launch_bounds__(256) void k1_embed(
    const float* __restrict__ x, const float* __restrict__ ul_wih,
    const float* __restrict__ ul_b, const float* __restrict__ uav_lin_w,
    const float* __restrict__ uav_lin_b, char* __restrict__ ws)
{
  __bf16* hb   = (__bf16*)(ws + OFF_HB);
  __bf16* acat = (__bf16*)(ws + OFF_ACAT);
  const int b = blockIdx.x, tid = threadIdx.x;
  if (b < 256) {
    const float* whhT = (const float*)(ws + OFF_WHHT);
    const int dir = tid >> 7, hc = tid & 127;
    const int u0 = b * 4;
    float wx[4], wy[4], bb[4];
#pragma unroll
    for (int g = 0; g < 4; ++g) {
      int row = g * 128 + hc;
      wx[g] = ul_wih[dir * 1024 + row * 2 + 0];
      wy[g] = ul_wih[dir * 1024 + row * 2 + 1];
      bb[g] = ul_b[dir * 512 + row];
    }
    __shared__ float h1s[2][128][4];  // [dir][k][user]
    float c1[4], h1v[4], in1x[4], in1y[4];
#pragma unroll
    for (int uu = 0; uu < 4; ++uu) {
      int u = u0 + uu;
      float ax = x[u * 2], ay = x[u * 2 + 1];
      float bx = x[(UQ + u) * 2], by = x[(UQ + u) * 2 + 1];
      float i0x = dir ? bx : ax, i0y = dir ? by : ay;
      in1x[uu] = dir ? ax : bx; in1y[uu] = dir ? ay : by;
      float gv[4];
#pragma unroll
      for (int g = 0; g < 4; ++g) gv[g] = wx[g] * i0x + wy[g] * i0y + bb[g];
      float ii = sigm(gv[0]), gg = tanhf(gv[2]), oo = sigm(gv[3]);
      c1[uu] = ii * gg;                    // c_prev = 0
      h1v[uu] = oo * tanhf(c1[uu]);
      h1s[dir][hc][uu] = h1v[uu];
    }
    __syncthreads();
    float acc[4][4];
#pragma unroll
    for (int uu = 0; uu < 4; ++uu)
#pragma unroll
      for (int g = 0; g < 4; ++g) acc[uu][g] = wx[g] * in1x[uu] + wy[g] * in1y[uu] + bb[g];
    for (int k = 0; k < 128; ++k) {
      f32x4 hv  = *(const f32x4*)&h1s[dir][k][0];
      f32x4 wv4 = *(const f32x4*)(whhT + dir * 65536 + k * 512 + hc * 4);
#pragma unroll
      for (int uu = 0; uu < 4; ++uu)
#pragma unroll
        for (int g = 0; g < 4; ++g) acc[uu][g] += hv[uu] * wv4[g];
    }
    const int col = dir * 128 + hc;
#pragma unroll
    for (int uu = 0; uu < 4; ++uu) {
      int u = u0 + uu;
      float ii = sigm(acc[uu][0]), ff = sigm(acc[uu][1]);
      float gg = tanhf(acc[uu][2]), oo = sigm(acc[uu][3]);
      float c2 = ff * c1[uu] + ii * gg;
      float h2v = oo * tanhf(c2);
      float va = dir ? h2v : h1v[uu];   // node u      = [hf0 | hr1]
      float vb = dir ? h1v[uu] : h2v;   // node U+u    = [hf1 | hr0]
      hb[u * HD + col] = (__bf16)va;
      hb[(UQ + u) * HD + col] = (__bf16)vb;
      acat[u * 512 + 256 + col] = (__bf16)va;
      acat[(UQ + u) * 512 + 256 + col] = (__bf16)vb;
      acat[u * 512 + tid] = (__bf16)0.f;          // agg part of users = 0
      acat[(UQ + u) * 512 + tid] = (__bf16)0.f;
    }
  } else {
    // UAV linear embed
    const int j = tid;
    for (int m = 0; m < MQ; ++m) {
      float xa = x[(NUQ + m) * 2], xb = x[(NUQ + m) * 2 + 1];
      float val = xa * uav_lin_w[j * 2] + xb * uav_lin_w[j * 2 + 1] + uav_lin_b[j];
      hb[(NUQ + m) * HD + j] = (__bf16)val;
      acat[(NUQ + m) * 512 + 256 + j] = (__bf16)val;
    }
  }
}

// =====================================================================
// Generic 128-row bf16 MFMA GEMM block: C[r][j] = A[r][:]·B[j][:] (+bias)(relu)
// A: [R][lda] bf16 row-major; B: [256][ldb] bf16 row-major (weights, K in rows)
// =====================================================================
__device__ __forceinline__ void gemm_block_128(
    const __bf16* __restrict__ A, int lda, int row0, int R,
    const __bf16* __restrict__ B, int ldb, int K,
    const float* __restrict__ bias, int relu,
    float* __restrict__ C, __bf16* __restrict__ Cb, int ldc)
{
  const int tid = threadIdx.x;
  const int wave = tid >> 6, lane = tid & 63;
  const int cl = lane & 15, kr = (lane >> 4) * 8;
  f32x4 acc[2][16];
#pragma unroll
  for (int g = 0; g < 2; ++g)
#pragma unroll
    for (int f = 0; f < 16; ++f) acc[g][f] = {0.f, 0.f, 0.f, 0.f};
  int trow[2];
#pragma unroll
  for (int g = 0; g < 2; ++g) {
    int t = row0 + wave * 32 + g * 16 + cl;
    trow[g] = t < R ? t : R - 1;
  }
  const int nk = K >> 5;
  for (int ks = 0; ks < nk; ++ks) {
    const int k0 = ks * 32 + kr;
    bf16x8 Af[2];
#pragma unroll
    for (int g = 0; g < 2; ++g) Af[g] = *(const bf16x8*)(A + trow[g] * lda + k0);
#pragma unroll
    for (int fh = 0; fh < 2; ++fh) {
      bf16x8 Bf[8];
#pragma unroll
      for (int f = 0; f < 8; ++f)
        Bf[f] = *(const bf16x8*)(B + (fh * 128 + f * 16 + cl) * ldb + k0);
#pragma unroll
      for (int g = 0; g < 2; ++g)
#pragma unroll
        for (int f = 0; f < 8; ++f)
          acc[g][fh * 8 + f] =
              __builtin_amdgcn_mfma_f32_16x16x32_bf16(Af[g], Bf[f], acc[g][fh * 8 + f], 0, 0, 0);
    }
  }
#pragma unroll
  for (int f = 0; f < 16; ++f) {
    const int j = f * 16 + cl;
    const float bj = bias ? bias[j] : 0.f;
#pragma unroll
    for (int g = 0; g < 2; ++g)
#pragma unroll
      for (int r = 0; r < 4; ++r) {
        int t = row0 + wave * 32 + g * 16 + (lane >> 4) * 4 + r;
        if (t < R) {
          float vv = acc[g][f][r] + bj;
          if (relu) vv = fmaxf(vv, 0.f);
          if (C)  C[t * ldc + j] = vv;
          if (Cb) Cb[t * ldc + j] = (__bf16)vv;
        }
      }
  }
}

// =====================================================================
// K2: P_user (16 blocks), P_uav+b1 (1 block), s'_m (1 block)
// =====================================================================
__global__ __launch_bounds__(256, 2) void k2_proj(const float* __restrict__ msg_b1,
                                                  char* __restrict__ ws)
{
  const __bf16* hb  = (const __bf16*)(ws + OFF_HB);
  const __bf16* mw1 = (const __bf16*)(ws + OFF_MW1);
  const int b = blockIdx.x;
  if (b < 16) {
    gemm_block_128(hb, 256, b * 128, 2048, mw1 + 256, 512, 256, nullptr, 0,
                   (float*)(ws + OFF_PU), nullptr, 256);
  } else if (b == 16) {
    gemm_block_128(hb + 2048 * 256, 256, 0, 64, mw1, 512, 256, msg_b1, 0,
                   (float*)(ws + OFF_PB), nullptr, 256);
  } else {
    const float* wqa = (const float*)(ws + OFF_ATT);
    const float* c0  = wqa + 512;
    float* spr = (float*)(ws + OFF_SPR);
    const int t = threadIdx.x;
    if (t < 64) {
      float s = 0.f;
      for (int k = 0; k < 256; ++k) s += (float)hb[(2048 + t) * 256 + k] * wqa[k];
      spr[t] = s + c0[0];
    }
  }
}

// =====================================================================
// K3: edge message layer-2 GEMM (bf16 MFMA) + attention + online softmax
// grid = 64 UAV * 16 chunks; block 256 (4 waves x 32 users), 128 users/chunk
// =====================================================================
__global__ __launch_bounds__(256, 2) void k3_edge(const float* __restrict__ msg_b2,
                                                  char* __restrict__ ws)
{
  const float*  PU  = (const float*)(ws + OFF_PU);
  const float*  PB  = (const float*)(ws + OFF_PB);
  const float*  spr = (const float*)(ws + OFF_SPR);
  const float*  vv  = (const float*)(ws + OFF_ATT) + 256;
  const __bf16* W2b = (const __bf16*)(ws + OFF_MW2);
  float* crec = (float*)(ws + OFF_CREC);

  const int m = blockIdx.x >> 4, ch = blockIdx.x & 15;
  const int tid = threadIdx.x, wave = tid >> 6, lane = tid & 63;
  const int cl = lane & 15, kr = (lane >> 4) * 8;
  const int tbase = ch * 128 + wave * 32;

  f32x4 acc[2][16];
#pragma unroll
  for (int g = 0; g < 2; ++g)
#pragma unroll
    for (int f = 0; f < 16; ++f) acc[g][f] = {0.f, 0.f, 0.f, 0.f};

  for (int ks = 0; ks < 8; ++ks) {
    const int k0 = ks * 32 + kr;
    f32x4 pb0 = *(const f32x4*)(PB + m * 256 + k0);
    f32x4 pb1 = *(const f32x4*)(PB + m * 256 + k0 + 4);
    bf16x8 Af[2];
#pragma unroll
    for (int g = 0; g < 2; ++g) {
      const float* pu = PU + (tbase + g * 16 + cl) * 256 + k0;
      f32x4 u0 = *(const f32x4*)pu;
      f32x4 u1 = *(const f32x4*)(pu + 4);
      bf16x8 a;
#pragma unroll
      for (int r = 0; r < 4; ++r) {
        a[r]     = (__bf16)fmaxf(u0[r] + pb0[r], 0.f);
        a[4 + r] = (__bf16)fmaxf(u1[r] + pb1[r], 0.f);
      }
      Af[g] = a;
    }
#pragma unroll
    for (int fh = 0; fh < 2; ++fh) {
      bf16x8 Bf[8];
#pragma unroll
      for (int f = 0; f < 8; ++f)
        Bf[f] = *(const bf16x8*)(W2b + (fh * 128 + f * 16 + cl) * 256 + k0);
#pragma unroll
      for (int g = 0; g < 2; ++g)
#pragma unroll
        for (int f = 0; f < 8; ++f)
          acc[g][fh * 8 + f] =
              __builtin_amdgcn_mfma_f32_16x16x32_bf16(Af[g], Bf[f], acc[g][fh * 8 + f], 0, 0, 0);
    }
  }

  // msg = relu(acc + b2); per-row logit partial = msg . v
  float p[2][4];
#pragma unroll
  for (int g = 0; g < 2; ++g)
#pragma unroll
    for (int r = 0; r < 4; ++r) p[g][r] = 0.f;
#pragma unroll
  for (int f = 0; f < 16; ++f) {
    const int j = f * 16 + cl;
    const float b2j = msg_b2[j], vj = vv[j];
#pragma unroll
    for (int g = 0; g < 2; ++g)
#pragma unroll
      for (int r = 0; r < 4; ++r) {
        float mv = fmaxf(acc[g][f][r] + b2j, 0.f);
        acc[g][f][r] = mv;
        p[g][r] += mv * vj;
      }
  }
#pragma unroll
  for (int mask = 1; mask < 16; mask <<= 1)
#pragma unroll
    for (int g = 0; g < 2; ++g)
#pragma unroll
      for (int r = 0; r < 4; ++r) p[g][r] += __shfl_xor(p[g][r], mask);

  const float sm = spr[m];
  float lr[2][4], wm = -3.4e38f;
#pragma unroll
  for (int g = 0; g < 2; ++g)
#pragma unroll
    for (int r = 0; r < 4; ++r) {
      float l = p[g][r] + sm;
      l = l > 0.f ? l : 0.2f * l;   // leaky relu BEFORE softmax
      lr[g][r] = l;
      wm = fmaxf(wm, l);
    }
  wm = fmaxf(wm, __shfl_xor(wm, 16));
  wm = fmaxf(wm, __shfl_xor(wm, 32));

  __shared__ float redmax[4], wds[4];
  __shared__ float wvs[4][256];
  if (lane == 0) redmax[wave] = wm;
  __syncthreads();
  const float Mc = fmaxf(fmaxf(redmax[0], redmax[1]), fmaxf(redmax[2], redmax[3]));

  float e[2][4], ds = 0.f;
#pragma unroll
  for (int g = 0; g < 2; ++g)
#pragma unroll
    for (int r = 0; r < 4; ++r) { e[g][r] = __expf(lr[g][r] - Mc); ds += e[g][r]; }
  ds += __shfl_xor(ds, 16);
  ds += __shfl_xor(ds, 32);

#pragma unroll
  for (int f = 0; f < 16; ++f) {
    float w = 0.f;
#pragma unroll
    for (int g = 0; g < 2; ++g)
#pragma unroll
      for (int r = 0; r < 4; ++r) w += e[g][r] * acc[g][f][r];
    w += __shfl_xor(w, 16);
    w += __shfl_xor(w, 32);
    if (lane < 16) wvs[wave][f * 16 + cl] = w;
  }
  if (lane == 0) wds[wave] = ds;
  __syncthreads();

  float* rec = crec + (m * 16 + ch) * 260;
  rec[tid] = wvs[0][tid] + wvs[1][tid] + wvs[2][tid] + wvs[3][tid];
  if (tid == 0) { rec[256] = Mc; rec[257] = wds[0] + wds[1] + wds[2] + wds[3]; }
}

// =====================================================================
// K4: combine 16 chunk partials per UAV -> agg, write into Acat (bf16)
// =====================================================================
__global__ __launch_bounds__(256) void k4_combine(char* __restrict__ ws)
{
  const float* crec = (const float*)(ws + OFF_CREC);
  __bf16* acat = (__bf16*)(ws + OFF_ACAT);
  const int m = blockIdx.x, j = threadIdx.x;
  float mx = -3.4e38f;
  for (int c = 0; c < 16; ++c) mx = fmaxf(mx, crec[(m * 16 + c) * 260 + 256]);
  float S = 0.f, A = 0.f;
  for (int c = 0; c < 16; ++c) {
    const float* rec = crec + (m * 16 + c) * 260;
    float sc = __expf(rec[256] - mx);
    S += sc * rec[257];
    A += sc * rec[j];
  }
  float agg = A / S * (1.f / 2048.f);   // softmax-weighted mean / degree
  acat[(2048 + m) * 512 + j] = (__bf16)agg;
}

// =====================================================================
// K5/K6: update MLP layers (bf16 MFMA GEMMs)
// =====================================================================
__global__ __launch_bounds__(256, 2) void k5_upd1(const float* __restrict__ upd_b1,
                                                  char* __restrict__ ws)
{
  gemm_block_128((const __bf16*)(ws + OFF_ACAT), 512, blockIdx.x * 128, NN,
                 (const __bf16*)(ws + OFF_UW1), 512, 512, upd_b1, 1,
                 nullptr, (__bf16*)(ws + OFF_L1B), 256);
}
__global__ __launch_bounds__(256, 2) void k6_upd2(const float* __restrict__ upd_b2,
                                                  char* __restrict__ ws)
{
  gemm_block_128((const __bf16*)(ws + OFF_L1B), 256, blockIdx.x * 128, NN,
                 (const __bf16*)(ws + OFF_UW2), 256, 256, upd_b2, 1,
                 (float*)(ws + OFF_H2), nullptr, 256);
}

// =====================================================================
// K7: UAV BiLSTM (T=1) + final linear + sigmoid for all rows
// =====================================================================
__global__ __launch_bounds__(256) void k7_final(
    const float* __restrict__ uavl_b, const float* __restrict__ lin2_w,
    const float* __restrict__ lin2_b, float* __restrict__ out, char* __restrict__ ws)
{
  const float* h2 = (const float*)(ws + OFF_H2);
  const int b = blockIdx.x, tid = threadIdx.x;
  if (b < 64) {
    const float* wihT = (const float*)(ws + OFF_WIHT);
    __shared__ float xs[256], uo[256];
    xs[tid] = h2[(2048 + b) * 256 + tid];
    __syncthreads();
    const int dir = tid >> 7, hc = tid & 127;
    float a4[4] = {0.f, 0.f, 0.f, 0.f};
    for (int k = 0; k < 256; ++k) {
      float xv = xs[k];
      f32x4 wv4 = *(const f32x4*)(wihT + dir * 131072 + k * 512 + hc * 4);
#pragma unroll
      for (int g = 0; g < 4; ++g) a4[g] += xv * wv4[g];
    }
    float bb[4];
#pragma unroll
    for (int g = 0; g < 4; ++g) bb[g] = uavl_b[dir * 512 + g * 128 + hc];
    // T=1: c = sig(i)*tanh(g), h = sig(o)*tanh(c)
    float ii = sigm(a4[0] + bb[0]);
    float gg = tanhf(a4[2] + bb[2]);
    float oo = sigm(a4[3] + bb[3]);
    float cc = ii * gg;
    uo[dir * 128 + hc] = oo * tanhf(cc);
    __syncthreads();
    float p0 = uo[tid] * lin2_w[tid];
    float p1 = uo[tid] * lin2_w[256 + tid];
#pragma unroll
    for (int mask = 1; mask < 64; mask <<= 1) {
      p0 += __shfl_xor(p0, mask);
      p1 += __shfl_xor(p1, mask);
    }
    __shared__ float r0s[4], r1s[4];
    const int lane = tid & 63, wv = tid >> 6;
    if (lane == 0) { r0s[wv] = p0; r1s[wv] = p1; }
    __syncthreads();
    if (tid == 0) {
      float d0 = r0s[0] + r0s[1] + r0s[2] + r0s[3] + lin2_b[0];
      float d1 = r1s[0] + r1s[1] + r1s[2] + r1s[3] + lin2_b[1];
      out[(2048 + b) * 2 + 0] = 1.f / (1.f + expf(-d0));
      out[(2048 + b) * 2 + 1] = 1.f / (1.f + expf(-d1));
    }
  } else {
    __shared__ float l0[256], l1[256];
    l0[tid] = lin2_w[tid];
    l1[tid] = lin2_w[256 + tid];
    __syncthreads();
    const int r = (b - 64) * 256 + tid;
    const float* hr = h2 + r * 256;
    float d0 = 0.f, d1 = 0.f;
    for (int k = 0; k < 256; k += 4) {
      f32x4 hv = *(const f32x4*)(hr + k);
#pragma unroll
      for (int q = 0; q < 4; ++q) { d0 += hv[q] * l0[k + q]; d1 += hv[q] * l1[k + q]; }
    }
    out[r * 2 + 0] = 1.f / (1.f + expf(-(d0 + lin2_b[0])));
    out[r * 2 + 1] = 1.f / (1.f + expf(-(d1 + lin2_b[1])));
  }
}

// =====================================================================
extern "C" void kernel_launch(void* const* d_in, const int* in_sizes, int n_in,
                              void* d_out, int out_size, void* d_ws, size_t ws_size,
                              hipStream_t stream)
{
  const float* x         = (const float*)d_in[0];
  // d_in[1] edge_index (implied structure), d_in[2] users_num (fixed 1024)
  const float* ul_wih    = (const float*)d_in[3];
  const float* ul_whh    = (const float*)d_in[4];
  const float* ul_b      = (const float*)d_in[5];
  const float* uav_lin_w = (const float*)d_in[6];
  const float* uav_lin_b = (const float*)d_in[7];
  const float* msg_w1    = (const float*)d_in[8];
  const float* msg_b1    = (const float*)d_in[9];
  const float* msg_w2    = (const float*)d_in[10];
  const float* msg_b2    = (const float*)d_in[11];
  const float* wq_w      = (const float*)d_in[12];
  const float* wq_b      = (const float*)d_in[13];
  const float* wr_w      = (const float*)d_in[14];
  const float* wr_b      = (const float*)d_in[15];
  const float* att_w     = (const float*)d_in[16];
  const float* att_b     = (const float*)d_in[17];
  const float* upd_w1    = (const float*)d_in[18];
  const float* upd_b1    = (const float*)d_in[19];
  const float* upd_w2    = (const float*)d_in[20];
  const float* upd_b2    = (const float*)d_in[21];
  const float* uavl_wih  = (const float*)d_in[22];
  const float* uavl_b    = (const float*)d_in[24];
  const float* lin2_w    = (const float*)d_in[25];
  const float* lin2_b    = (const float*)d_in[26];
  char* ws = (char*)d_ws;
  float* out = (float*)d_out;

  k0_prep<<<dim3(49), dim3(256), 0, stream>>>(ul_whh, uavl_wih, msg_w1, msg_w2, upd_w1,
                                              upd_w2, att_w, att_b, wq_w, wq_b, wr_w, wr_b, ws);
  k1_embed<<<dim3(257), dim3(256), 0, stream>>>(x, ul_wih, ul_b, uav_lin_w, uav_lin_b, ws);
  k2_proj<<<dim3(18), dim3(256), 0, stream>>>(msg_b1, ws);
  k3_edge<<<dim3(1024), dim3(256), 0, stream>>>(msg_b2, ws);
  k4_combine<<<dim3(64), dim3(256), 0, stream>>>(ws);
  k5_upd1<<<dim3(17), dim3(256), 0, stream>>>(upd_b1, ws);
  k6_upd2<<<dim3(17), dim3(256), 0, stream>>>(upd_b2, ws);
  k7_final<<<dim3(72), dim3(256), 0, stream>>>(uavl_b, lin2_w, lin2_b, out, ws);
}

// Round 2
// 140.670 us; speedup vs baseline: 1.6731x; 1.6731x over previous
//
#include <hip/hip_runtime.h>
#include <hip/hip_bf16.h>
#include <math.h>

// Problem constants (fixed instance)
#define UQ   1024     // user pairs
#define NUQ  2048     // 2U user nodes
#define MQ   64       // UAV nodes
#define NN   2112     // total nodes
#define HD   256      // hidden
#define NCH  8        // chunks per UAV in edge kernel (256 users each)

typedef __attribute__((ext_vector_type(4))) float f32x4;
typedef __attribute__((ext_vector_type(8))) __bf16 bf16x8;

// ---- workspace layout (bytes, all 256-aligned) ----
#define OFF_HB    0u          // h bf16 [2112][256]              1,081,344
#define OFF_ACAT  1081344u    // Acat bf16 [2112][512] = [agg|h] 2,162,688
#define OFF_PU    3244032u    // P_user bf16 [2048][256]         1,048,576
#define OFF_PB    5341184u    // P_uav+b1 f32 [64][256]             65,536
#define OFF_SPR   5406720u    // s'_m f32 [64]                        256
#define OFF_ATT   5406976u    // wqa[256], v[256], const0           2,304
#define OFF_WHHT  5409280u    // user WhhT2 f32 [2][128][512]     524,288
#define OFF_WIHT  5933568u    // uav WihT2 f32 [2][256][512]    1,048,576
#define OFF_MW1   6982144u    // msg_w1 bf16 [256][512]           262,144
#define OFF_MW2   7244288u    // W2F blocked bf16 [8][256][32]    131,072
#define OFF_UW1   7375360u    // upd_w1 bf16 [256][512]           262,144
#define OFF_UW2   7637504u    // upd_w2 bf16 [256][256]           131,072
#define OFF_CREC  7768576u    // chunk rec f32 [512][260]         532,480
#define OFF_L1B   8833536u    // upd layer1 bf16 [2112][256]    1,081,344
#define OFF_H2    9914880u    // h2 f32 [2112][256]             2,162,688

__device__ __forceinline__ float sigm(float v) { return 1.f / (1.f + expf(-v)); }

// =====================================================================
// K0: weight preprocessing (transposes, bf16 casts, W2 k-slice blocking)
// =====================================================================
__global__ __launch_bounds__(256) void k0_prep(
    const float* __restrict__ ul_whh, const float* __restrict__ uavl_wih,
    const float* __restrict__ msg_w1, const float* __restrict__ msg_w2,
    const float* __restrict__ upd_w1, const float* __restrict__ upd_w2,
    const float* __restrict__ att_w,  const float* __restrict__ att_b,
    const float* __restrict__ wq_w,   const float* __restrict__ wq_b,
    const float* __restrict__ wr_w,   const float* __restrict__ wr_b,
    char* __restrict__ ws)
{
  const int b = blockIdx.x, t = threadIdx.x;
  if (b < 8) {
    float* o = (float*)(ws + OFF_WHHT);
    for (int idx = b * 16384 + t; idx < (b + 1) * 16384; idx += 256) {
      int dir = idx >> 16, rem = idx & 65535;
      int k = rem >> 9, hc4 = rem & 511;
      int hc = hc4 >> 2, g = hc4 & 3;
      o[idx] = ul_whh[dir * 65536 + (g * 128 + hc) * 128 + k];
    }
  } else if (b < 24) {
    float* o = (float*)(ws + OFF_WIHT);
    const int b2 = b - 8;
    for (int idx = b2 * 16384 + t; idx < (b2 + 1) * 16384; idx += 256) {
      int dir = idx >> 17, rem = idx & 131071;
      int k = rem >> 9, hc4 = rem & 511;
      int hc = hc4 >> 2, g = hc4 & 3;
      o[idx] = uavl_wih[dir * 131072 + (g * 128 + hc) * 256 + k];
    }
  } else if (b < 32) {
    __bf16* o = (__bf16*)(ws + OFF_MW1); const int b2 = b - 24;
    for (int idx = b2 * 16384 + t; idx < (b2 + 1) * 16384; idx += 256) o[idx] = (__bf16)msg_w1[idx];
  } else if (b < 36) {
    // W2F blocked: tile ks holds W2[j][ks*32 .. ks*32+31], row-major 32 wide
    __bf16* o = (__bf16*)(ws + OFF_MW2); const int b2 = b - 32;
    for (int idx = b2 * 16384 + t; idx < (b2 + 1) * 16384; idx += 256) {
      int j = idx >> 8, k = idx & 255;
      o[(k >> 5) * 8192 + j * 32 + (k & 31)] = (__bf16)msg_w2[idx];
    }
  } else if (b < 44) {
    __bf16* o = (__bf16*)(ws + OFF_UW1); const int b2 = b - 36;
    for (int idx = b2 * 16384 + t; idx < (b2 + 1) * 16384; idx += 256) o[idx] = (__bf16)upd_w1[idx];
  } else if (b < 48) {
    __bf16* o = (__bf16*)(ws + OFF_UW2); const int b2 = b - 44;
    for (int idx = b2 * 16384 + t; idx < (b2 + 1) * 16384; idx += 256) o[idx] = (__bf16)upd_w2[idx];
  } else {
    float* wqa = (float*)(ws + OFF_ATT);
    float* vv  = wqa + 256;
    float* c0  = wqa + 512;
    float sa = 0.f, sr = 0.f;
    for (int j = 0; j < 256; ++j) {
      sa += att_w[j]       * wq_w[j * 256 + t];
      sr += att_w[256 + j] * wr_w[j * 256 + t];
    }
    wqa[t] = sa; vv[t] = sr;
    __shared__ float red[256];
    red[t] = att_w[t] * wq_b[t] + att_w[256 + t] * wr_b[t];
    __syncthreads();
    for (int s = 128; s > 0; s >>= 1) { if (t < s) red[t] += red[t + s]; __syncthreads(); }
    if (t == 0) c0[0] = red[0] + att_b[0];
  }
}

// =====================================================================
// K1: user BiLSTM (4 users/block) + UAV linear embed; writes h_bf16, Acat
// =====================================================================
__global__ __launch_bounds__(256) void k1_embed(
    const float* __restrict__ x, const float* __restrict__ ul_wih,
    const float* __restrict__ ul_b, const float* __restrict__ uav_lin_w,
    const float* __restrict__ uav_lin_b, char* __restrict__ ws)
{
  __bf16* hb   = (__bf16*)(ws + OFF_HB);
  __bf16* acat = (__bf16*)(ws + OFF_ACAT);
  const int b = blockIdx.x, tid = threadIdx.x;
  if (b < 256) {
    const float* whhT = (const float*)(ws + OFF_WHHT);
    const int dir = tid >> 7, hc = tid & 127;
    const int u0 = b * 4;
    float wx[4], wy[4], bb[4];
#pragma unroll
    for (int g = 0; g < 4; ++g) {
      int row = g * 128 + hc;
      wx[g] = ul_wih[dir * 1024 + row * 2 + 0];
      wy[g] = ul_wih[dir * 1024 + row * 2 + 1];
      bb[g] = ul_b[dir * 512 + row];
    }
    __shared__ float h1s[2][128][4];
    float c1[4], h1v[4], in1x[4], in1y[4];
#pragma unroll
    for (int uu = 0; uu < 4; ++uu) {
      int u = u0 + uu;
      float ax = x[u * 2], ay = x[u * 2 + 1];
      float bx = x[(UQ + u) * 2], by = x[(UQ + u) * 2 + 1];
      float i0x = dir ? bx : ax, i0y = dir ? by : ay;
      in1x[uu] = dir ? ax : bx; in1y[uu] = dir ? ay : by;
      float gv[4];
#pragma unroll
      for (int g = 0; g < 4; ++g) gv[g] = wx[g] * i0x + wy[g] * i0y + bb[g];
      float ii = sigm(gv[0]), gg = tanhf(gv[2]), oo = sigm(gv[3]);
      c1[uu] = ii * gg;
      h1v[uu] = oo * tanhf(c1[uu]);
      h1s[dir][hc][uu] = h1v[uu];
    }
    __syncthreads();
    float acc[4][4];
#pragma unroll
    for (int uu = 0; uu < 4; ++uu)
#pragma unroll
      for (int g = 0; g < 4; ++g) acc[uu][g] = wx[g] * in1x[uu] + wy[g] * in1y[uu] + bb[g];
    for (int k = 0; k < 128; ++k) {
      f32x4 hv  = *(const f32x4*)&h1s[dir][k][0];
      f32x4 wv4 = *(const f32x4*)(whhT + dir * 65536 + k * 512 + hc * 4);
#pragma unroll
      for (int uu = 0; uu < 4; ++uu)
#pragma unroll
        for (int g = 0; g < 4; ++g) acc[uu][g] += hv[uu] * wv4[g];
    }
    const int col = dir * 128 + hc;
#pragma unroll
    for (int uu = 0; uu < 4; ++uu) {
      int u = u0 + uu;
      float ii = sigm(acc[uu][0]), ff = sigm(acc[uu][1]);
      float gg = tanhf(acc[uu][2]), oo = sigm(acc[uu][3]);
      float c2 = ff * c1[uu] + ii * gg;
      float h2v = oo * tanhf(c2);
      float va = dir ? h2v : h1v[uu];
      float vb = dir ? h1v[uu] : h2v;
      hb[u * HD + col] = (__bf16)va;
      hb[(UQ + u) * HD + col] = (__bf16)vb;
      acat[u * 512 + 256 + col] = (__bf16)va;
      acat[(UQ + u) * 512 + 256 + col] = (__bf16)vb;
      acat[u * 512 + tid] = (__bf16)0.f;
      acat[(UQ + u) * 512 + tid] = (__bf16)0.f;
    }
  } else {
    const int j = tid;
    for (int m = 0; m < MQ; ++m) {
      float xa = x[(NUQ + m) * 2], xb = x[(NUQ + m) * 2 + 1];
      float val = xa * uav_lin_w[j * 2] + xb * uav_lin_w[j * 2 + 1] + uav_lin_b[j];
      hb[(NUQ + m) * HD + j] = (__bf16)val;
      acat[(NUQ + m) * 512 + 256 + j] = (__bf16)val;
    }
  }
}

// =====================================================================
// Templated MFMA GEMM tile: 4 waves x (G*16 rows) x (F*16 cols)
// A [R][lda] bf16 row-major; B [256][ldb] bf16 (out_j rows, k cols)
// =====================================================================
template<int G, int F>
__device__ __forceinline__ void gemm_tile(
    const __bf16* __restrict__ A, int lda, int row0, int R,
    const __bf16* __restrict__ B, int ldb, int K, int col0,
    const float* __restrict__ bias, int relu,
    float* __restrict__ C, __bf16* __restrict__ Cb, int ldc)
{
  const int tid = threadIdx.x;
  const int wave = tid >> 6, lane = tid & 63;
  const int cl = lane & 15, g16 = lane >> 4;
  f32x4 acc[G][F];
#pragma unroll
  for (int g = 0; g < G; ++g)
#pragma unroll
    for (int f = 0; f < F; ++f) acc[g][f] = {0.f, 0.f, 0.f, 0.f};
  int trow[G];
#pragma unroll
  for (int g = 0; g < G; ++g) {
    int t = row0 + wave * (G * 16) + g * 16 + cl;
    trow[g] = t < R ? t : R - 1;
  }
  const int nk = K >> 5;
  for (int ks = 0; ks < nk; ++ks) {
    const int k0 = ks * 32 + g16 * 8;
    bf16x8 Af[G];
#pragma unroll
    for (int g = 0; g < G; ++g) Af[g] = *(const bf16x8*)(A + trow[g] * lda + k0);
    bf16x8 Bf[F];
#pragma unroll
    for (int f = 0; f < F; ++f)
      Bf[f] = *(const bf16x8*)(B + (col0 + f * 16 + cl) * ldb + k0);
#pragma unroll
    for (int g = 0; g < G; ++g)
#pragma unroll
      for (int f = 0; f < F; ++f)
        acc[g][f] = __builtin_amdgcn_mfma_f32_16x16x32_bf16(Af[g], Bf[f], acc[g][f], 0, 0, 0);
  }
#pragma unroll
  for (int f = 0; f < F; ++f) {
    const int j = col0 + f * 16 + cl;
    const float bj = bias ? bias[j] : 0.f;
#pragma unroll
    for (int g = 0; g < G; ++g)
#pragma unroll
      for (int r = 0; r < 4; ++r) {
        int t = row0 + wave * (G * 16) + g * 16 + g16 * 4 + r;
        if (t < R) {
          float vv = acc[g][f][r] + bj;
          if (relu) vv = fmaxf(vv, 0.f);
          if (C)  C[t * ldc + j] = vv;
          if (Cb) Cb[t * ldc + j] = (__bf16)vv;
        }
      }
  }
}

// =====================================================================
// K2: P_user bf16 (64 blocks), P_uav+b1 (2 blocks), s'_m (1 block)
// =====================================================================
__global__ __launch_bounds__(256, 4) void k2_proj(const float* __restrict__ msg_b1,
                                                  char* __restrict__ ws)
{
  const __bf16* hb  = (const __bf16*)(ws + OFF_HB);
  const __bf16* mw1 = (const __bf16*)(ws + OFF_MW1);
  const int b = blockIdx.x;
  if (b < 64) {
    gemm_tile<1, 8>(hb, 256, (b >> 1) * 64, 2048, mw1 + 256, 512, 256, (b & 1) * 128,
                    nullptr, 0, nullptr, (__bf16*)(ws + OFF_PU), 256);
  } else if (b < 66) {
    gemm_tile<1, 8>(hb + 2048 * 256, 256, 0, 64, mw1, 512, 256, (b & 1) * 128,
                    msg_b1, 0, (float*)(ws + OFF_PB), nullptr, 256);
  } else {
    const float* wqa = (const float*)(ws + OFF_ATT);
    const float* c0  = wqa + 512;
    float* spr = (float*)(ws + OFF_SPR);
    const int t = threadIdx.x;
    if (t < 64) {
      float s = 0.f;
      for (int k = 0; k < 256; ++k) s += (float)hb[(2048 + t) * 256 + k] * wqa[k];
      spr[t] = s + c0[0];
    }
  }
}

// =====================================================================
// K3: edge message layer-2 GEMM with LDS-staged W2 (double-buffered),
// fused attention + chunk-level online softmax.
// grid = 64 m * 8 chunks; 512 threads = 8 waves (4 rowgrp x 2 colgrp),
// each wave 64 rows x 128 cols. W2 tile [256][32] bf16, 80B row stride.
// =====================================================================
__global__ __launch_bounds__(512, 2) void k3_edge(const float* __restrict__ msg_b2,
                                                  char* __restrict__ ws)
{
  const __bf16* PUb = (const __bf16*)(ws + OFF_PU);
  const float*  PB  = (const float*)(ws + OFF_PB);
  const float*  spr = (const float*)(ws + OFF_SPR);
  const float*  vv  = (const float*)(ws + OFF_ATT) + 256;
  const char*   W2F = (const char*)(ws + OFF_MW2);
  float* crec = (float*)(ws + OFF_CREC);

  __shared__ f32x4 smem4[2560];          // 2 x 20480B W2 tiles (80B row stride)
  char* smem = (char*)smem4;
  __shared__ float plds[8][64];
  __shared__ float redmax[8], wds[8];

  const int m = blockIdx.x >> 3, ch = blockIdx.x & 7;
  const int tid = threadIdx.x, wave = tid >> 6, lane = tid & 63;
  const int cl = lane & 15, g16 = lane >> 4;
  const int rg = wave >> 1, cg = wave & 1;
  const int rowbase = ch * 256 + rg * 64;
  const float sm = spr[m];

  const int stw = (tid >> 1) * 80 + (tid & 1) * 32;   // LDS dest (swizzled pad)
  // prologue: stage ks=0 tile, prefetch A(ks=0)
  {
    f32x4 s0 = *(const f32x4*)(W2F + tid * 32);
    f32x4 s1 = *(const f32x4*)(W2F + tid * 32 + 16);
    *(f32x4*)(smem + stw) = s0;
    *(f32x4*)(smem + stw + 16) = s1;
  }
  bf16x8 ar[4];
#pragma unroll
  for (int g = 0; g < 4; ++g)
    ar[g] = *(const bf16x8*)(PUb + (rowbase + g * 16 + cl) * 256 + g16 * 8);
  __syncthreads();

  f32x4 acc[4][8];
#pragma unroll
  for (int g = 0; g < 4; ++g)
#pragma unroll
    for (int f = 0; f < 8; ++f) acc[g][f] = {0.f, 0.f, 0.f, 0.f};

  int cur = 0;
  for (int ks = 0; ks < 8; ++ks) {
    f32x4 st0 = {}, st1 = {};
    bf16x8 arn[4];
    if (ks < 7) {
      st0 = *(const f32x4*)(W2F + (ks + 1) * 16384 + tid * 32);
      st1 = *(const f32x4*)(W2F + (ks + 1) * 16384 + tid * 32 + 16);
#pragma unroll
      for (int g = 0; g < 4; ++g)
        arn[g] = *(const bf16x8*)(PUb + (rowbase + g * 16 + cl) * 256 + (ks + 1) * 32 + g16 * 8);
    }
    const float* pbp = PB + m * 256 + ks * 32 + g16 * 8;
    f32x4 pb0 = *(const f32x4*)pbp;
    f32x4 pb1 = *(const f32x4*)(pbp + 4);
    bf16x8 Af[4];
#pragma unroll
    for (int g = 0; g < 4; ++g) {
      bf16x8 a;
#pragma unroll
      for (int r = 0; r < 4; ++r) {
        a[r]     = (__bf16)fmaxf((float)ar[g][r]     + pb0[r], 0.f);
        a[4 + r] = (__bf16)fmaxf((float)ar[g][4 + r] + pb1[r], 0.f);
      }
      Af[g] = a;
    }
    const char* buf = smem + cur * 20480;
    bf16x8 Bf[8];
#pragma unroll
    for (int f = 0; f < 8; ++f)
      Bf[f] = *(const bf16x8*)(buf + (cg * 128 + f * 16 + cl) * 80 + g16 * 16);
#pragma unroll
    for (int g = 0; g < 4; ++g)
#pragma unroll
      for (int f = 0; f < 8; ++f)
        acc[g][f] = __builtin_amdgcn_mfma_f32_16x16x32_bf16(Af[g], Bf[f], acc[g][f], 0, 0, 0);
    if (ks < 7) {
      char* nbuf = smem + (cur ^ 1) * 20480;
      *(f32x4*)(nbuf + stw) = st0;
      *(f32x4*)(nbuf + stw + 16) = st1;
#pragma unroll
      for (int g = 0; g < 4; ++g) ar[g] = arn[g];
    }
    __syncthreads();
    cur ^= 1;
  }

  // msg = relu(acc + b2); per-row logit partial over this wave's 128 cols
  float p[4][4];
#pragma unroll
  for (int g = 0; g < 4; ++g)
#pragma unroll
    for (int r = 0; r < 4; ++r) p[g][r] = 0.f;
#pragma unroll
  for (int f = 0; f < 8; ++f) {
    const int j = cg * 128 + f * 16 + cl;
    const float b2j = msg_b2[j], vj = vv[j];
#pragma unroll
    for (int g = 0; g < 4; ++g)
#pragma unroll
      for (int r = 0; r < 4; ++r) {
        float mv = fmaxf(acc[g][f][r] + b2j, 0.f);
        acc[g][f][r] = mv;
        p[g][r] += mv * vj;
      }
  }
#pragma unroll
  for (int mask = 1; mask < 16; mask <<= 1)
#pragma unroll
    for (int g = 0; g < 4; ++g)
#pragma unroll
      for (int r = 0; r < 4; ++r) p[g][r] += __shfl_xor(p[g][r], mask);
#pragma unroll
  for (int g = 0; g < 4; ++g)
#pragma unroll
    for (int r = 0; r < 4; ++r)
      plds[wave][g * 16 + g16 * 4 + r] = p[g][r];   // same value across cl lanes
  __syncthreads();

  // per-lane logits for its rows (g, g16, r); chunk max
  float lr[4][4], wm = -3.4e38f;
#pragma unroll
  for (int g = 0; g < 4; ++g)
#pragma unroll
    for (int r = 0; r < 4; ++r) {
      int li = g * 16 + g16 * 4 + r;
      float l = plds[rg * 2][li] + plds[rg * 2 + 1][li] + sm;
      l = l > 0.f ? l : 0.2f * l;     // leaky relu before softmax
      lr[g][r] = l;
      wm = fmaxf(wm, l);
    }
  wm = fmaxf(wm, __shfl_xor(wm, 16));
  wm = fmaxf(wm, __shfl_xor(wm, 32));
  if (lane == 0) redmax[wave] = wm;
  __syncthreads();
  float Mc = redmax[0];
#pragma unroll
  for (int i = 1; i < 8; ++i) Mc = fmaxf(Mc, redmax[i]);

  float e[4][4], ds = 0.f;
#pragma unroll
  for (int g = 0; g < 4; ++g)
#pragma unroll
    for (int r = 0; r < 4; ++r) { e[g][r] = __expf(lr[g][r] - Mc); ds += e[g][r]; }
  ds += __shfl_xor(ds, 16);
  ds += __shfl_xor(ds, 32);

  float* wvs = (float*)smem;   // [8][128], aliases W2 tiles (all reads done)
#pragma unroll
  for (int f = 0; f < 8; ++f) {
    float w = 0.f;
#pragma unroll
    for (int g = 0; g < 4; ++g)
#pragma unroll
      for (int r = 0; r < 4; ++r) w += e[g][r] * acc[g][f][r];
    w += __shfl_xor(w, 16);
    w += __shfl_xor(w, 32);
    if (g16 == 0) wvs[wave * 128 + f * 16 + cl] = w;
  }
  if (lane == 0 && cg == 0) wds[wave] = ds;
  __syncthreads();

  float* rec = crec + (m * 8 + ch) * 260;
  if (tid < 256) {
    int cgj = tid >> 7, jj = tid & 127;
    rec[tid] = wvs[(0 + cgj) * 128 + jj] + wvs[(2 + cgj) * 128 + jj] +
               wvs[(4 + cgj) * 128 + jj] + wvs[(6 + cgj) * 128 + jj];
  }
  if (tid == 0) { rec[256] = Mc; rec[257] = wds[0] + wds[2] + wds[4] + wds[6]; }
}

// =====================================================================
// K4: combine 8 chunk partials per UAV -> agg, write into Acat (bf16)
// =====================================================================
__global__ __launch_bounds__(256) void k4_combine(char* __restrict__ ws)
{
  const float* crec = (const float*)(ws + OFF_CREC);
  __bf16* acat = (__bf16*)(ws + OFF_ACAT);
  const int m = blockIdx.x, j = threadIdx.x;
  float mx = -3.4e38f;
  for (int c = 0; c < 8; ++c) mx = fmaxf(mx, crec[(m * 8 + c) * 260 + 256]);
  float S = 0.f, A = 0.f;
  for (int c = 0; c < 8; ++c) {
    const float* rec = crec + (m * 8 + c) * 260;
    float sc = __expf(rec[256] - mx);
    S += sc * rec[257];
    A += sc * rec[j];
  }
  float agg = A / S * (1.f / 2048.f);
  acat[(2048 + m) * 512 + j] = (__bf16)agg;
}

// =====================================================================
// K5/K6: update MLP layers (64-row x 128-col tiles, 66 blocks each)
// =====================================================================
__global__ __launch_bounds__(256, 4) void k5_upd1(const float* __restrict__ upd_b1,
                                                  char* __restrict__ ws)
{
  const int b = blockIdx.x;
  gemm_tile<1, 8>((const __bf16*)(ws + OFF_ACAT), 512, (b >> 1) * 64, NN,
                  (const __bf16*)(ws + OFF_UW1), 512, 512, (b & 1) * 128,
                  upd_b1, 1, nullptr, (__bf16*)(ws + OFF_L1B), 256);
}
__global__ __launch_bounds__(256, 4) void k6_upd2(const float* __restrict__ upd_b2,
                                                  char* __restrict__ ws)
{
  const int b = blockIdx.x;
  gemm_tile<1, 8>((const __bf16*)(ws + OFF_L1B), 256, (b >> 1) * 64, NN,
                  (const __bf16*)(ws + OFF_UW2), 256, 256, (b & 1) * 128,
                  upd_b2, 1, (float*)(ws + OFF_H2), nullptr, 256);
}

// =====================================================================
// K7: UAV BiLSTM (T=1) + final linear + sigmoid for all rows
// =====================================================================
__global__ __launch_bounds__(256) void k7_final(
    const float* __restrict__ uavl_b, const float* __restrict__ lin2_w,
    const float* __restrict__ lin2_b, float* __restrict__ out, char* __restrict__ ws)
{
  const float* h2 = (const float*)(ws + OFF_H2);
  const int b = blockIdx.x, tid = threadIdx.x;
  if (b < 64) {
    const float* wihT = (const float*)(ws + OFF_WIHT);
    __shared__ float xs[256], uo[256];
    xs[tid] = h2[(2048 + b) * 256 + tid];
    __syncthreads();
    const int dir = tid >> 7, hc = tid & 127;
    float a4[4] = {0.f, 0.f, 0.f, 0.f};
    for (int k = 0; k < 256; ++k) {
      float xv = xs[k];
      f32x4 wv4 = *(const f32x4*)(wihT + dir * 131072 + k * 512 + hc * 4);
#pragma unroll
      for (int g = 0; g < 4; ++g) a4[g] += xv * wv4[g];
    }
    float bb[4];
#pragma unroll
    for (int g = 0; g < 4; ++g) bb[g] = uavl_b[dir * 512 + g * 128 + hc];
    float ii = sigm(a4[0] + bb[0]);
    float gg = tanhf(a4[2] + bb[2]);
    float oo = sigm(a4[3] + bb[3]);
    float cc = ii * gg;
    uo[dir * 128 + hc] = oo * tanhf(cc);
    __syncthreads();
    float p0 = uo[tid] * lin2_w[tid];
    float p1 = uo[tid] * lin2_w[256 + tid];
#pragma unroll
    for (int mask = 1; mask < 64; mask <<= 1) {
      p0 += __shfl_xor(p0, mask);
      p1 += __shfl_xor(p1, mask);
    }
    __shared__ float r0s[4], r1s[4];
    const int lane = tid & 63, wv = tid >> 6;
    if (lane == 0) { r0s[wv] = p0; r1s[wv] = p1; }
    __syncthreads();
    if (tid == 0) {
      float d0 = r0s[0] + r0s[1] + r0s[2] + r0s[3] + lin2_b[0];
      float d1 = r1s[0] + r1s[1] + r1s[2] + r1s[3] + lin2_b[1];
      out[(2048 + b) * 2 + 0] = 1.f / (1.f + expf(-d0));
      out[(2048 + b) * 2 + 1] = 1.f / (1.f + expf(-d1));
    }
  } else {
    __shared__ float l0[256], l1[256];
    l0[tid] = lin2_w[tid];
    l1[tid] = lin2_w[256 + tid];
    __syncthreads();
    const int r = (b - 64) * 256 + tid;
    const float* hr = h2 + r * 256;
    float d0 = 0.f, d1 = 0.f;
    for (int k = 0; k < 256; k += 4) {
      f32x4 hv = *(const f32x4*)(hr + k);
#pragma unroll
      for (int q = 0; q < 4; ++q) { d0 += hv[q] * l0[k + q]; d1 += hv[q] * l1[k + q]; }
    }
    out[r * 2 + 0] = 1.f / (1.f + expf(-(d0 + lin2_b[0])));
    out[r * 2 + 1] = 1.f / (1.f + expf(-(d1 + lin2_b[1])));
  }
}

// =====================================================================
extern "C" void kernel_launch(void* const* d_in, const int* in_sizes, int n_in,
                              void* d_out, int out_size, void* d_ws, size_t ws_size,
                              hipStream_t stream)
{
  const float* x         = (const float*)d_in[0];
  const float* ul_wih    = (const float*)d_in[3];
  const float* ul_whh    = (const float*)d_in[4];
  const float* ul_b      = (const float*)d_in[5];
  const float* uav_lin_w = (const float*)d_in[6];
  const float* uav_lin_b = (const float*)d_in[7];
  const float* msg_w1    = (const float*)d_in[8];
  const float* msg_b1    = (const float*)d_in[9];
  const float* msg_w2    = (const float*)d_in[10];
  const float* msg_b2    = (const float*)d_in[11];
  const float* wq_w      = (const float*)d_in[12];
  const float* wq_b      = (const float*)d_in[13];
  const float* wr_w      = (const float*)d_in[14];
  const float* wr_b      = (const float*)d_in[15];
  const float* att_w     = (const float*)d_in[16];
  const float* att_b     = (const float*)d_in[17];
  const float* upd_w1    = (const float*)d_in[18];
  const float* upd_b1    = (const float*)d_in[19];
  const float* upd_w2    = (const float*)d_in[20];
  const float* upd_b2    = (const float*)d_in[21];
  const float* uavl_wih  = (const float*)d_in[22];
  const float* uavl_b    = (const float*)d_in[24];
  const float* lin2_w    = (const float*)d_in[25];
  const float* lin2_b    = (const float*)d_in[26];
  char* ws = (char*)d_ws;
  float* out = (float*)d_out;

  k0_prep<<<dim3(49), dim3(256), 0, stream>>>(ul_whh, uavl_wih, msg_w1, msg_w2, upd_w1,
                                              upd_w2, att_w, att_b, wq_w, wq_b, wr_w, wr_b, ws);
  k1_embed<<<dim3(257), dim3(256), 0, stream>>>(x, ul_wih, ul_b, uav_lin_w, uav_lin_b, ws);
  k2_proj<<<dim3(67), dim3(256), 0, stream>>>(msg_b1, ws);
  k3_edge<<<dim3(512), dim3(512), 0, stream>>>(msg_b2, ws);
  k4_combine<<<dim3(64), dim3(256), 0, stream>>>(ws);
  k5_upd1<<<dim3(66), dim3(256), 0, stream>>>(upd_b1, ws);
  k6_upd2<<<dim3(66), dim3(256), 0, stream>>>(upd_b2, ws);
  k7_final<<<dim3(72), dim3(256), 0, stream>>>(uavl_b, lin2_w, lin2_b, out, ws);
}

// Round 3
// 114.610 us; speedup vs baseline: 2.0535x; 1.2274x over previous
//
#include <hip/hip_runtime.h>
#include <hip/hip_bf16.h>
#include <math.h>

#define UQ   1024
#define NUQ  2048
#define MQ   64
#define NN   2112
#define HD   256

typedef __attribute__((ext_vector_type(4))) float f32x4;
typedef __attribute__((ext_vector_type(8))) __bf16 bf16x8;

// ---- workspace layout (bytes) ----
#define OFF_HB    0u          // UAV h f32 [64][256]                 65,536
#define OFF_HUF   65536u      // h frag bf16 [33][8][4][512]      1,081,344
#define OFF_ACATF 1146880u    // Acat frag bf16 [33][16][4][512]  2,162,688
#define OFF_PUBF  3309568u    // P_user frag bf16 [8][8][16][512] 1,048,576
#define OFF_PB    4358144u    // P_uav+b1 f32 [64][256]              65,536
#define OFF_SPR   4423680u    // s'_m f32 [64]                          256
#define OFF_ATT   4423936u    // wqa[256], v[256], const0             2,304
#define OFF_WHHT  4426240u    // user WhhT2 f32 [2][128][512]       524,288
#define OFF_WIHT  4950528u    // uav WihT2 f32 [2][256][512]      1,048,576
#define OFF_W1F   5999104u    // msg_w1 frag bf16 [16][16][512]     262,144
#define OFF_W2F   6261248u    // msg_w2 frag bf16 [8][16][512]      131,072
#define OFF_UW1F  6392320u    // upd_w1 frag bf16 [16][16][512]     262,144
#define OFF_UW2F  6654464u    // upd_w2 frag bf16 [8][16][512]      131,072
#define OFF_L1BF  6785536u    // layer1 frag bf16 [33][8][4][512] 1,081,344
#define OFF_CREC  7866880u    // chunk rec f32 [512][260]           532,480
#define OFF_H2    8399360u    // h2 f32 [2112][256]               2,162,688
// total ~10.6 MB

__device__ __forceinline__ float sigm(float v) { return 1.f / (1.f + expf(-v)); }

// fragment-major index helpers: element (row, k)
__device__ __forceinline__ int huf_idx(int row, int k) {   // [33][8][4][512]
  return (((row >> 6) * 8 + (k >> 5)) * 4 + ((row >> 4) & 3)) * 512 +
         (((k >> 3) & 3) * 16 + (row & 15)) * 8 + (k & 7);
}
__device__ __forceinline__ int acatf_idx(int row, int k) { // [33][16][4][512]
  return (((row >> 6) * 16 + (k >> 5)) * 4 + ((row >> 4) & 3)) * 512 +
         (((k >> 3) & 3) * 16 + (row & 15)) * 8 + (k & 7);
}
__device__ __forceinline__ int pubf_idx(int row, int k) {  // [8][8][16][512]
  return (((row >> 8) * 8 + (k >> 5)) * 16 + ((row >> 4) & 15)) * 512 +
         (((k >> 3) & 3) * 16 + (row & 15)) * 8 + (k & 7);
}

__device__ __forceinline__ void gl16(const void* g, void* l) {
  __builtin_amdgcn_global_load_lds((const __attribute__((address_space(1))) void*)g,
                                   (__attribute__((address_space(3))) void*)l, 16, 0, 0);
}

// =====================================================================
// K0: weight preprocessing — LDS-tiled transposes + fragment-major casts
// =====================================================================
__device__ void tile_transpose_perm(const float* __restrict__ in, int in_ld,
                                    float* __restrict__ out, int out_ld,
                                    int k0, int c0) {
  // out[k][c] = in[(c&3)*128 + (c>>2)][k], 64x64 tile
  __shared__ float ldt[64][68];
  const int t = threadIdx.x;
  {
    const int ci = t >> 2, kq = t & 3;
    const int c = c0 + ci;
    const int row = (c & 3) * 128 + (c >> 2);
    const float* src = in + row * in_ld + k0 + kq * 16;
#pragma unroll
    for (int e = 0; e < 4; ++e)
      *(f32x4*)&ldt[ci][kq * 16 + e * 4] = *(const f32x4*)(src + e * 4);
  }
  __syncthreads();
  {
    const int kk = t >> 2, cq = t & 3;
    float* dst = out + (k0 + kk) * out_ld + c0 + cq * 16;
#pragma unroll
    for (int e4 = 0; e4 < 4; ++e4) {
      f32x4 v;
#pragma unroll
      for (int j = 0; j < 4; ++j) v[j] = ldt[cq * 16 + e4 * 4 + j][kk];
      *(f32x4*)(dst + e4 * 4) = v;
    }
  }
}

template<int K>
__device__ void frag_cast16(const float* __restrict__ W, int j0, __bf16* __restrict__ frag) {
  // rows j0..j0+15 of W[256][K] -> frag[(ks*16 + f)*512 + lane*8 + e], f = j0>>4
  __shared__ float ldc[16][K + 4];
  const int t = threadIdx.x;
  {
    const int jr = t >> 4, kq = t & 15;
    const float* src = W + (j0 + jr) * K + kq * (K / 16);
#pragma unroll
    for (int e = 0; e < K / 64; ++e)
      *(f32x4*)&ldc[jr][kq * (K / 16) + e * 4] = *(const f32x4*)(src + e * 4);
  }
  __syncthreads();
  const int f = j0 >> 4;
  constexpr int nks = K >> 5;
  constexpr int thr_per_ks = 256 / nks;
  constexpr int q_per_thr = 512 / thr_per_ks;
  const int ks = t / thr_per_ks;
  const int q0 = (t % thr_per_ks) * q_per_thr;
#pragma unroll
  for (int h = 0; h < q_per_thr / 8; ++h) {
    bf16x8 v;
#pragma unroll
    for (int e = 0; e < 8; ++e) {
      int q = q0 + h * 8 + e;
      int lane = q >> 3;
      v[e] = (__bf16)ldc[lane & 15][ks * 32 + (lane >> 4) * 8 + (q & 7)];
    }
    *(bf16x8*)(frag + (ks * 16 + f) * 512 + q0 + h * 8) = v;
  }
}

__global__ __launch_bounds__(256) void k0_prep(
    const float* __restrict__ ul_whh, const float* __restrict__ uavl_wih,
    const float* __restrict__ msg_w1, const float* __restrict__ msg_w2,
    const float* __restrict__ upd_w1, const float* __restrict__ upd_w2,
    const float* __restrict__ att_w,  const float* __restrict__ att_b,
    const float* __restrict__ wq_w,   const float* __restrict__ wq_b,
    const float* __restrict__ wr_w,   const float* __restrict__ wr_b,
    char* __restrict__ ws)
{
  const int b = blockIdx.x, t = threadIdx.x;
  if (b < 32) {
    const int dir = b >> 4, tile = b & 15;
    tile_transpose_perm(ul_whh + dir * 65536, 128,
                        (float*)(ws + OFF_WHHT) + dir * 65536, 512,
                        (tile >> 3) * 64, (tile & 7) * 64);
  } else if (b < 96) {
    const int b2 = b - 32, dir = b2 >> 5, tile = b2 & 31;
    tile_transpose_perm(uavl_wih + dir * 131072, 256,
                        (float*)(ws + OFF_WIHT) + dir * 131072, 512,
                        (tile >> 3) * 64, (tile & 7) * 64);
  } else if (b < 112) {
    frag_cast16<256>(msg_w2, (b - 96) * 16, (__bf16*)(ws + OFF_W2F));
  } else if (b < 128) {
    frag_cast16<512>(msg_w1, (b - 112) * 16, (__bf16*)(ws + OFF_W1F));
  } else if (b < 144) {
    frag_cast16<512>(upd_w1, (b - 128) * 16, (__bf16*)(ws + OFF_UW1F));
  } else if (b < 160) {
    frag_cast16<256>(upd_w2, (b - 144) * 16, (__bf16*)(ws + OFF_UW2F));
  } else {
    float* wqa = (float*)(ws + OFF_ATT);
    float* vv  = wqa + 256;
    float* c0  = wqa + 512;
    float sa = 0.f, sr = 0.f;
    for (int j = 0; j < 256; ++j) {
      sa += att_w[j]       * wq_w[j * 256 + t];
      sr += att_w[256 + j] * wr_w[j * 256 + t];
    }
    wqa[t] = sa; vv[t] = sr;
    __shared__ float red[256];
    red[t] = att_w[t] * wq_b[t] + att_w[256 + t] * wr_b[t];
    __syncthreads();
    for (int s = 128; s > 0; s >>= 1) { if (t < s) red[t] += red[t + s]; __syncthreads(); }
    if (t == 0) c0[0] = red[0] + att_b[0];
  }
}

// =====================================================================
// K1: user BiLSTM (4 users/block) + UAV linear embed; frag-major writes
// =====================================================================
__global__ __launch_bounds__(256) void k1_embed(
    const float* __restrict__ x, const float* __restrict__ ul_wih,
    const float* __restrict__ ul_b, const float* __restrict__ uav_lin_w,
    const float* __restrict__ uav_lin_b, char* __restrict__ ws)
{
  __bf16* huf   = (__bf16*)(ws + OFF_HUF);
  __bf16* acatf = (__bf16*)(ws + OFF_ACATF);
  const int b = blockIdx.x, tid = threadIdx.x;
  if (b < 256) {
    const float* whhT = (const float*)(ws + OFF_WHHT);
    const int dir = tid >> 7, hc = tid & 127;
    const int u0 = b * 4;
    float wx[4], wy[4], bb[4];
#pragma unroll
    for (int g = 0; g < 4; ++g) {
      int row = g * 128 + hc;
      wx[g] = ul_wih[dir * 1024 + row * 2 + 0];
      wy[g] = ul_wih[dir * 1024 + row * 2 + 1];
      bb[g] = ul_b[dir * 512 + row];
    }
    __shared__ float h1s[2][128][4];
    float c1[4], h1v[4], in1x[4], in1y[4];
#pragma unroll
    for (int uu = 0; uu < 4; ++uu) {
      int u = u0 + uu;
      float ax = x[u * 2], ay = x[u * 2 + 1];
      float bx = x[(UQ + u) * 2], by = x[(UQ + u) * 2 + 1];
      float i0x = dir ? bx : ax, i0y = dir ? by : ay;
      in1x[uu] = dir ? ax : bx; in1y[uu] = dir ? ay : by;
      float gv[4];
#pragma unroll
      for (int g = 0; g < 4; ++g) gv[g] = wx[g] * i0x + wy[g] * i0y + bb[g];
      float ii = sigm(gv[0]), gg = tanhf(gv[2]), oo = sigm(gv[3]);
      c1[uu] = ii * gg;
      h1v[uu] = oo * tanhf(c1[uu]);
      h1s[dir][hc][uu] = h1v[uu];
    }
    __syncthreads();
    float acc[4][4];
#pragma unroll
    for (int uu = 0; uu < 4; ++uu)
#pragma unroll
      for (int g = 0; g < 4; ++g) acc[uu][g] = wx[g] * in1x[uu] + wy[g] * in1y[uu] + bb[g];
    for (int k = 0; k < 128; ++k) {
      f32x4 hv  = *(const f32x4*)&h1s[dir][k][0];
      f32x4 wv4 = *(const f32x4*)(whhT + dir * 65536 + k * 512 + hc * 4);
#pragma unroll
      for (int uu = 0; uu < 4; ++uu)
#pragma unroll
        for (int g = 0; g < 4; ++g) acc[uu][g] += hv[uu] * wv4[g];
    }
    const int col = dir * 128 + hc;
#pragma unroll
    for (int uu = 0; uu < 4; ++uu) {
      int u = u0 + uu;
      float ii = sigm(acc[uu][0]), ff = sigm(acc[uu][1]);
      float gg = tanhf(acc[uu][2]), oo = sigm(acc[uu][3]);
      float c2 = ff * c1[uu] + ii * gg;
      float h2v = oo * tanhf(c2);
      float va = dir ? h2v : h1v[uu];
      float vb = dir ? h1v[uu] : h2v;
      huf[huf_idx(u, col)] = (__bf16)va;
      huf[huf_idx(UQ + u, col)] = (__bf16)vb;
      acatf[acatf_idx(u, 256 + col)] = (__bf16)va;
      acatf[acatf_idx(UQ + u, 256 + col)] = (__bf16)vb;
      acatf[acatf_idx(u, tid)] = (__bf16)0.f;
      acatf[acatf_idx(UQ + u, tid)] = (__bf16)0.f;
    }
  } else {
    float* hb = (float*)(ws + OFF_HB);
    const int j = tid;
    const int mb = (b - 256) * 16;
    for (int m = mb; m < mb + 16; ++m) {
      float xa = x[(NUQ + m) * 2], xb = x[(NUQ + m) * 2 + 1];
      float val = xa * uav_lin_w[j * 2] + xb * uav_lin_w[j * 2 + 1] + uav_lin_b[j];
      hb[m * 256 + j] = val;
      huf[huf_idx(NUQ + m, j)] = (__bf16)val;
      acatf[acatf_idx(NUQ + m, 256 + j)] = (__bf16)val;
    }
  }
}

// =====================================================================
// frag-major MFMA GEMM core: 256 thr = 4 waves (cg), 64 rows x 256 cols
// =====================================================================
template<int NKS>
__device__ __forceinline__ void frag_gemm_acc(const __bf16* __restrict__ Abase,
                                              const __bf16* __restrict__ Bbase,
                                              f32x4 acc[4][4]) {
  const int lane = threadIdx.x & 63;
  const int cg = threadIdx.x >> 6;
  for (int ks = 0; ks < NKS; ++ks) {
    bf16x8 Af[4], Bf[4];
#pragma unroll
    for (int g = 0; g < 4; ++g)
      Af[g] = *(const bf16x8*)(Abase + ((ks * 4 + g) * 64 + lane) * 8);
#pragma unroll
    for (int f = 0; f < 4; ++f)
      Bf[f] = *(const bf16x8*)(Bbase + ((ks * 16 + cg * 4 + f) * 64 + lane) * 8);
#pragma unroll
    for (int g = 0; g < 4; ++g)
#pragma unroll
      for (int f = 0; f < 4; ++f)
        acc[g][f] = __builtin_amdgcn_mfma_f32_16x16x32_bf16(Af[g], Bf[f], acc[g][f], 0, 0, 0);
  }
}

// =====================================================================
// K2: P_user frag (32 blocks), P_uav+b1 (1), s'_m (1)
// =====================================================================
__global__ __launch_bounds__(256) void k2_proj(const float* __restrict__ msg_b1,
                                               char* __restrict__ ws)
{
  const __bf16* huf = (const __bf16*)(ws + OFF_HUF);
  const __bf16* w1f = (const __bf16*)(ws + OFF_W1F);
  const int b = blockIdx.x;
  const int lane = threadIdx.x & 63, cg = threadIdx.x >> 6;
  const int cl = lane & 15, g16 = lane >> 4;
  if (b < 32) {
    f32x4 acc[4][4] = {};
    frag_gemm_acc<8>(huf + b * 16384, w1f + 65536, acc);
    __bf16* pubf = (__bf16*)(ws + OFF_PUBF);
#pragma unroll
    for (int g = 0; g < 4; ++g)
#pragma unroll
      for (int f = 0; f < 4; ++f)
#pragma unroll
        for (int r = 0; r < 4; ++r) {
          int row = b * 64 + g * 16 + g16 * 4 + r;
          int col = cg * 64 + f * 16 + cl;
          pubf[pubf_idx(row, col)] = (__bf16)acc[g][f][r];
        }
  } else if (b == 32) {
    f32x4 acc[4][4] = {};
    frag_gemm_acc<8>(huf + 32 * 16384, w1f, acc);
    float* pb = (float*)(ws + OFF_PB);
#pragma unroll
    for (int g = 0; g < 4; ++g)
#pragma unroll
      for (int f = 0; f < 4; ++f)
#pragma unroll
        for (int r = 0; r < 4; ++r) {
          int row = g * 16 + g16 * 4 + r;
          int col = cg * 64 + f * 16 + cl;
          pb[row * 256 + col] = acc[g][f][r] + msg_b1[col];
        }
  } else {
    const float* hb  = (const float*)(ws + OFF_HB);
    const float* wqa = (const float*)(ws + OFF_ATT);
    const float* c0  = wqa + 512;
    float* spr = (float*)(ws + OFF_SPR);
    const int t = threadIdx.x;
    if (t < 64) {
      float s = 0.f;
      for (int k = 0; k < 256; ++k) s += hb[t * 256 + k] * wqa[k];
      spr[t] = s + c0[0];
    }
  }
}

// =====================================================================
// K3: edge msg layer-2 + attention + chunk softmax.
// 1024 thr = 16 waves (4 rg x 4 cg), 256 rows x 256 cols per block,
// global_load_lds double-buffered frag-major A(raw PU) and B(W2) tiles.
// grid = 64 m * 8 chunks
// =====================================================================
__global__ __launch_bounds__(1024) void k3_edge(const float* __restrict__ msg_b2,
                                                char* __restrict__ ws)
{
  const char*  PUBF = (const char*)(ws + OFF_PUBF);
  const float* PB   = (const float*)(ws + OFF_PB);
  const float* spr  = (const float*)(ws + OFF_SPR);
  const float* vv   = (const float*)(ws + OFF_ATT) + 256;
  const char*  W2F  = (const char*)(ws + OFF_W2F);
  float* crec = (float*)(ws + OFF_CREC);

  __shared__ __align__(16) char bufA[2][16384];
  __shared__ __align__(16) char bufB[2][16384];
  __shared__ float plds[16][64];
  __shared__ float redmax[16], wds[16];
  __shared__ float wvs[4][256];

  const int m = blockIdx.x >> 3, ch = blockIdx.x & 7;
  const int tid = threadIdx.x, wave = tid >> 6, lane = tid & 63;
  const int cl = lane & 15, g16 = lane >> 4;
  const int rg = wave >> 2, cg = wave & 3;
  const float sm = spr[m];
  const char* Asrc = PUBF + ch * 131072;   // [8 ks][16KB]

  // prologue: stage ks=0
  gl16(Asrc + wave * 1024 + lane * 16, &bufA[0][wave * 1024]);
  gl16(W2F  + wave * 1024 + lane * 16, &bufB[0][wave * 1024]);
  __syncthreads();

  f32x4 acc[4][4] = {};
  for (int ks = 0; ks < 8; ++ks) {
    const int cur = ks & 1;
    if (ks < 7) {
      gl16(Asrc + (ks + 1) * 16384 + wave * 1024 + lane * 16, &bufA[cur ^ 1][wave * 1024]);
      gl16(W2F  + (ks + 1) * 16384 + wave * 1024 + lane * 16, &bufB[cur ^ 1][wave * 1024]);
    }
    const float* pbp = PB + m * 256 + ks * 32 + g16 * 8;
    f32x4 pb0 = *(const f32x4*)pbp;
    f32x4 pb1 = *(const f32x4*)(pbp + 4);
    bf16x8 Af[4];
#pragma unroll
    for (int g = 0; g < 4; ++g) {
      bf16x8 raw = *(const bf16x8*)(&bufA[cur][((rg * 4 + g) * 64 + lane) * 16]);
      bf16x8 a;
#pragma unroll
      for (int r = 0; r < 4; ++r) {
        a[r]     = (__bf16)fmaxf((float)raw[r]     + pb0[r], 0.f);
        a[4 + r] = (__bf16)fmaxf((float)raw[4 + r] + pb1[r], 0.f);
      }
      Af[g] = a;
    }
    bf16x8 Bf[4];
#pragma unroll
    for (int f = 0; f < 4; ++f)
      Bf[f] = *(const bf16x8*)(&bufB[cur][((cg * 4 + f) * 64 + lane) * 16]);
#pragma unroll
    for (int g = 0; g < 4; ++g)
#pragma unroll
      for (int f = 0; f < 4; ++f)
        acc[g][f] = __builtin_amdgcn_mfma_f32_16x16x32_bf16(Af[g], Bf[f], acc[g][f], 0, 0, 0);
    __syncthreads();
  }

  // msg = relu(acc + b2); logit partial over this wave's 64 cols
  float p[4][4] = {};
#pragma unroll
  for (int f = 0; f < 4; ++f) {
    const int j = cg * 64 + f * 16 + cl;
    const float b2j = msg_b2[j], vj = vv[j];
#pragma unroll
    for (int g = 0; g < 4; ++g)
#pragma unroll
      for (int r = 0; r < 4; ++r) {
        float mv = fmaxf(acc[g][f][r] + b2j, 0.f);
        acc[g][f][r] = mv;
        p[g][r] += mv * vj;
      }
  }
#pragma unroll
  for (int mask = 1; mask < 16; mask <<= 1)
#pragma unroll
    for (int g = 0; g < 4; ++g)
#pragma unroll
      for (int r = 0; r < 4; ++r) p[g][r] += __shfl_xor(p[g][r], mask);
  if (cl == 0) {
#pragma unroll
    for (int g = 0; g < 4; ++g)
#pragma unroll
      for (int r = 0; r < 4; ++r) plds[wave][g * 16 + g16 * 4 + r] = p[g][r];
  }
  __syncthreads();

  float lr[4][4], wm = -3.4e38f;
#pragma unroll
  for (int g = 0; g < 4; ++g)
#pragma unroll
    for (int r = 0; r < 4; ++r) {
      int row = g * 16 + g16 * 4 + r;
      float l = plds[rg * 4 + 0][row] + plds[rg * 4 + 1][row] +
                plds[rg * 4 + 2][row] + plds[rg * 4 + 3][row] + sm;
      l = l > 0.f ? l : 0.2f * l;
      lr[g][r] = l;
      wm = fmaxf(wm, l);
    }
  wm = fmaxf(wm, __shfl_xor(wm, 16));
  wm = fmaxf(wm, __shfl_xor(wm, 32));
  if (lane == 0) redmax[wave] = wm;
  __syncthreads();
  float Mc = redmax[0];
#pragma unroll
  for (int i = 1; i < 16; ++i) Mc = fmaxf(Mc, redmax[i]);

  float e[4][4], ds = 0.f;
#pragma unroll
  for (int g = 0; g < 4; ++g)
#pragma unroll
    for (int r = 0; r < 4; ++r) { e[g][r] = __expf(lr[g][r] - Mc); ds += e[g][r]; }
  ds += __shfl_xor(ds, 16);
  ds += __shfl_xor(ds, 32);
  if (lane == 0) wds[wave] = ds;

#pragma unroll
  for (int f = 0; f < 4; ++f) {
    float w = 0.f;
#pragma unroll
    for (int g = 0; g < 4; ++g)
#pragma unroll
      for (int r = 0; r < 4; ++r) w += e[g][r] * acc[g][f][r];
    w += __shfl_xor(w, 16);
    w += __shfl_xor(w, 32);
    if (g16 == 0) wvs[rg][cg * 64 + f * 16 + cl] = w;
  }
  __syncthreads();

  float* rec = crec + (m * 8 + ch) * 260;
  if (tid < 256) rec[tid] = wvs[0][tid] + wvs[1][tid] + wvs[2][tid] + wvs[3][tid];
  if (tid == 0) rec[256] = Mc;
  if (tid == 1) rec[257] = wds[0] + wds[4] + wds[8] + wds[12];
}

// =====================================================================
// K4: combine 8 chunk partials per UAV -> agg into ACATF
// =====================================================================
__global__ __launch_bounds__(256) void k4_combine(char* __restrict__ ws)
{
  const float* crec = (const float*)(ws + OFF_CREC);
  __bf16* acatf = (__bf16*)(ws + OFF_ACATF);
  const int m = blockIdx.x, j = threadIdx.x;
  float mx = -3.4e38f;
  for (int c = 0; c < 8; ++c) mx = fmaxf(mx, crec[(m * 8 + c) * 260 + 256]);
  float S = 0.f, A = 0.f;
  for (int c = 0; c < 8; ++c) {
    const float* rec = crec + (m * 8 + c) * 260;
    float sc = __expf(rec[256] - mx);
    S += sc * rec[257];
    A += sc * rec[j];
  }
  float agg = A / S * (1.f / 2048.f);
  acatf[acatf_idx(NUQ + m, j)] = (__bf16)agg;
}

// =====================================================================
// K5/K6: update MLP layers (frag-major, 33 blocks each)
// =====================================================================
__global__ __launch_bounds__(256) void k5_upd1(const float* __restrict__ upd_b1,
                                               char* __restrict__ ws)
{
  const int b = blockIdx.x;
  const int lane = threadIdx.x & 63, cg = threadIdx.x >> 6;
  const int cl = lane & 15, g16 = lane >> 4;
  f32x4 acc[4][4] = {};
  frag_gemm_acc<16>((const __bf16*)(ws + OFF_ACATF) + b * 32768,
                    (const __bf16*)(ws + OFF_UW1F), acc);
  __bf16* l1bf = (__bf16*)(ws + OFF_L1BF);
#pragma unroll
  for (int g = 0; g < 4; ++g)
#pragma unroll
    for (int f = 0; f < 4; ++f)
#pragma unroll
      for (int r = 0; r < 4; ++r) {
        int row = b * 64 + g * 16 + g16 * 4 + r;
        int col = cg * 64 + f * 16 + cl;
        float v = fmaxf(acc[g][f][r] + upd_b1[col], 0.f);
        l1bf[huf_idx(row, col)] = (__bf16)v;
      }
}
__global__ __launch_bounds__(256) void k6_upd2(const float* __restrict__ upd_b2,
                                               char* __restrict__ ws)
{
  const int b = blockIdx.x;
  const int lane = threadIdx.x & 63, cg = threadIdx.x >> 6;
  const int cl = lane & 15, g16 = lane >> 4;
  f32x4 acc[4][4] = {};
  frag_gemm_acc<8>((const __bf16*)(ws + OFF_L1BF) + b * 16384,
                   (const __bf16*)(ws + OFF_UW2F), acc);
  float* h2 = (float*)(ws + OFF_H2);
#pragma unroll
  for (int g = 0; g < 4; ++g)
#pragma unroll
    for (int f = 0; f < 4; ++f)
#pragma unroll
      for (int r = 0; r < 4; ++r) {
        int row = b * 64 + g * 16 + g16 * 4 + r;
        int col = cg * 64 + f * 16 + cl;
        h2[row * 256 + col] = fmaxf(acc[g][f][r] + upd_b2[col], 0.f);
      }
}

// =====================================================================
// K7: UAV BiLSTM (T=1) + final linear + sigmoid
// =====================================================================
__global__ __launch_bounds__(256) void k7_final(
    const float* __restrict__ uavl_b, const float* __restrict__ lin2_w,
    const float* __restrict__ lin2_b, float* __restrict__ out, char* __restrict__ ws)
{
  const float* h2 = (const float*)(ws + OFF_H2);
  const int b = blockIdx.x, tid = threadIdx.x;
  if (b < 64) {
    const float* wihT = (const float*)(ws + OFF_WIHT);
    __shared__ float xs[256], uo[256];
    xs[tid] = h2[(NUQ + b) * 256 + tid];
    __syncthreads();
    const int dir = tid >> 7, hc = tid & 127;
    float a4[4] = {0.f, 0.f, 0.f, 0.f};
    for (int k = 0; k < 256; ++k) {
      float xv = xs[k];
      f32x4 wv4 = *(const f32x4*)(wihT + dir * 131072 + k * 512 + hc * 4);
#pragma unroll
      for (int g = 0; g < 4; ++g) a4[g] += xv * wv4[g];
    }
    float bb[4];
#pragma unroll
    for (int g = 0; g < 4; ++g) bb[g] = uavl_b[dir * 512 + g * 128 + hc];
    float ii = sigm(a4[0] + bb[0]);
    float gg = tanhf(a4[2] + bb[2]);
    float oo = sigm(a4[3] + bb[3]);
    float cc = ii * gg;
    uo[dir * 128 + hc] = oo * tanhf(cc);
    __syncthreads();
    float p0 = uo[tid] * lin2_w[tid];
    float p1 = uo[tid] * lin2_w[256 + tid];
#pragma unroll
    for (int mask = 1; mask < 64; mask <<= 1) {
      p0 += __shfl_xor(p0, mask);
      p1 += __shfl_xor(p1, mask);
    }
    __shared__ float r0s[4], r1s[4];
    const int lane = tid & 63, wv = tid >> 6;
    if (lane == 0) { r0s[wv] = p0; r1s[wv] = p1; }
    __syncthreads();
    if (tid == 0) {
      float d0 = r0s[0] + r0s[1] + r0s[2] + r0s[3] + lin2_b[0];
      float d1 = r1s[0] + r1s[1] + r1s[2] + r1s[3] + lin2_b[1];
      out[(NUQ + b) * 2 + 0] = 1.f / (1.f + expf(-d0));
      out[(NUQ + b) * 2 + 1] = 1.f / (1.f + expf(-d1));
    }
  } else {
    __shared__ float l0s[256], l1s[256];
    l0s[tid] = lin2_w[tid];
    l1s[tid] = lin2_w[256 + tid];
    __syncthreads();
    const int row = (b - 64) * 32 + (tid >> 3);
    const int sub = tid & 7;
    const float* hr = h2 + row * 256;
    float d0 = 0.f, d1 = 0.f;
#pragma unroll
    for (int i = 0; i < 8; ++i) {
      int k = i * 32 + sub * 4;
      f32x4 hv = *(const f32x4*)(hr + k);
#pragma unroll
      for (int q = 0; q < 4; ++q) { d0 += hv[q] * l0s[k + q]; d1 += hv[q] * l1s[k + q]; }
    }
#pragma unroll
    for (int mask = 1; mask < 8; mask <<= 1) {
      d0 += __shfl_xor(d0, mask);
      d1 += __shfl_xor(d1, mask);
    }
    if (sub == 0) {
      out[row * 2 + 0] = 1.f / (1.f + expf(-(d0 + lin2_b[0])));
      out[row * 2 + 1] = 1.f / (1.f + expf(-(d1 + lin2_b[1])));
    }
  }
}

// =====================================================================
extern "C" void kernel_launch(void* const* d_in, const int* in_sizes, int n_in,
                              void* d_out, int out_size, void* d_ws, size_t ws_size,
                              hipStream_t stream)
{
  const float* x         = (const float*)d_in[0];
  const float* ul_wih    = (const float*)d_in[3];
  const float* ul_whh    = (const float*)d_in[4];
  const float* ul_b      = (const float*)d_in[5];
  const float* uav_lin_w = (const float*)d_in[6];
  const float* uav_lin_b = (const float*)d_in[7];
  const float* msg_w1    = (const float*)d_in[8];
  const float* msg_b1    = (const float*)d_in[9];
  const float* msg_w2    = (const float*)d_in[10];
  const float* msg_b2    = (const float*)d_in[11];
  const float* wq_w      = (const float*)d_in[12];
  const float* wq_b      = (const float*)d_in[13];
  const float* wr_w      = (const float*)d_in[14];
  const float* wr_b      = (const float*)d_in[15];
  const float* att_w     = (const float*)d_in[16];
  const float* att_b     = (const float*)d_in[17];
  const float* upd_w1    = (const float*)d_in[18];
  const float* upd_b1    = (const float*)d_in[19];
  const float* upd_w2    = (const float*)d_in[20];
  const float* upd_b2    = (const float*)d_in[21];
  const float* uavl_wih  = (const float*)d_in[22];
  const float* uavl_b    = (const float*)d_in[24];
  const float* lin2_w    = (const float*)d_in[25];
  const float* lin2_b    = (const float*)d_in[26];
  char* ws = (char*)d_ws;
  float* out = (float*)d_out;

  k0_prep<<<dim3(161), dim3(256), 0, stream>>>(ul_whh, uavl_wih, msg_w1, msg_w2, upd_w1,
                                               upd_w2, att_w, att_b, wq_w, wq_b, wr_w, wr_b, ws);
  k1_embed<<<dim3(260), dim3(256), 0, stream>>>(x, ul_wih, ul_b, uav_lin_w, uav_lin_b, ws);
  k2_proj<<<dim3(34), dim3(256), 0, stream>>>(msg_b1, ws);
  k3_edge<<<dim3(512), dim3(1024), 0, stream>>>(msg_b2, ws);
  k4_combine<<<dim3(64), dim3(256), 0, stream>>>(ws);
  k5_upd1<<<dim3(33), dim3(256), 0, stream>>>(upd_b1, ws);
  k6_upd2<<<dim3(33), dim3(256), 0, stream>>>(upd_b2, ws);
  k7_final<<<dim3(128), dim3(256), 0, stream>>>(uavl_b, lin2_w, lin2_b, out, ws);
}

// Round 4
// 110.840 us; speedup vs baseline: 2.1234x; 1.0340x over previous
//
#include <hip/hip_runtime.h>
#include <hip/hip_bf16.h>
#include <math.h>

#define UQ   1024
#define NUQ  2048
#define MQ   64
#define NN   2112
#define HD   256

typedef __attribute__((ext_vector_type(4))) float f32x4;
typedef __attribute__((ext_vector_type(8))) __bf16 bf16x8;

// ---- workspace layout (bytes) ----
#define OFF_HB    0u          // UAV h f32 [64][256]                65,536
#define OFF_HUF   65536u      // h frag bf16 [33][8][4][512]     1,081,344
#define OFF_PUBF  1146880u    // P_user frag bf16 [8][8][16][512]1,048,576
#define OFF_PB    2195456u    // P_uav+b1 f32 [64][256]             65,536
#define OFF_SPR   2260992u    // s'_m f32 [64]                         256
#define OFF_ATT   2261248u    // wqa[256], v[256], const0            2,304
#define OFF_WHHT  2263552u    // user WhhT2 f32 [2][128][512]      524,288
#define OFF_WIHT  2787840u    // uav WihT2 f32 [2][256][512]     1,048,576
#define OFF_W1F   3836416u    // msg_w1 frag bf16 [16][16][512]    262,144
#define OFF_W2F   4098560u    // msg_w2 frag bf16 [8][16][512]     131,072
#define OFF_UW1F  4229632u    // upd_w1 frag bf16 [16][16][512]    262,144
#define OFF_UW2F  4491776u    // upd_w2 frag bf16 [8][16][512]     131,072
#define OFF_CREC  4622848u    // chunk rec f32 [512][260]          532,480
#define OFF_H2U   5155328u    // h2 UAV f32 [64][256]               65,536
// total ~5.2 MB

__device__ __forceinline__ float sigm(float v) { return 1.f / (1.f + expf(-v)); }

// fragment-major index helpers: element (row, k)
__device__ __forceinline__ int huf_idx(int row, int k) {   // [33][8][4][512]
  return (((row >> 6) * 8 + (k >> 5)) * 4 + ((row >> 4) & 3)) * 512 +
         (((k >> 3) & 3) * 16 + (row & 15)) * 8 + (k & 7);
}
__device__ __forceinline__ int pubf_idx(int row, int k) {  // [8][8][16][512]
  return (((row >> 8) * 8 + (k >> 5)) * 16 + ((row >> 4) & 15)) * 512 +
         (((k >> 3) & 3) * 16 + (row & 15)) * 8 + (k & 7);
}

__device__ __forceinline__ void gl16(const void* g, void* l) {
  __builtin_amdgcn_global_load_lds((const __attribute__((address_space(1))) void*)g,
                                   (__attribute__((address_space(3))) void*)l, 16, 0, 0);
}

// =====================================================================
// K0: weight preprocessing — LDS-tiled transposes + fragment-major casts
// =====================================================================
__device__ void tile_transpose_perm(const float* __restrict__ in, int in_ld,
                                    float* __restrict__ out, int out_ld,
                                    int k0, int c0) {
  __shared__ float ldt[64][68];
  const int t = threadIdx.x;
  {
    const int ci = t >> 2, kq = t & 3;
    const int c = c0 + ci;
    const int row = (c & 3) * 128 + (c >> 2);
    const float* src = in + row * in_ld + k0 + kq * 16;
#pragma unroll
    for (int e = 0; e < 4; ++e)
      *(f32x4*)&ldt[ci][kq * 16 + e * 4] = *(const f32x4*)(src + e * 4);
  }
  __syncthreads();
  {
    const int kk = t >> 2, cq = t & 3;
    float* dst = out + (k0 + kk) * out_ld + c0 + cq * 16;
#pragma unroll
    for (int e4 = 0; e4 < 4; ++e4) {
      f32x4 v;
#pragma unroll
      for (int j = 0; j < 4; ++j) v[j] = ldt[cq * 16 + e4 * 4 + j][kk];
      *(f32x4*)(dst + e4 * 4) = v;
    }
  }
}

template<int K>
__device__ void frag_cast16(const float* __restrict__ W, int j0, __bf16* __restrict__ frag) {
  __shared__ float ldc[16][K + 4];
  const int t = threadIdx.x;
  {
    const int jr = t >> 4, kq = t & 15;
    const float* src = W + (j0 + jr) * K + kq * (K / 16);
#pragma unroll
    for (int e = 0; e < K / 64; ++e)
      *(f32x4*)&ldc[jr][kq * (K / 16) + e * 4] = *(const f32x4*)(src + e * 4);
  }
  __syncthreads();
  const int f = j0 >> 4;
  constexpr int nks = K >> 5;
  constexpr int thr_per_ks = 256 / nks;
  constexpr int q_per_thr = 512 / thr_per_ks;
  const int ks = t / thr_per_ks;
  const int q0 = (t % thr_per_ks) * q_per_thr;
#pragma unroll
  for (int h = 0; h < q_per_thr / 8; ++h) {
    bf16x8 v;
#pragma unroll
    for (int e = 0; e < 8; ++e) {
      int q = q0 + h * 8 + e;
      int lane = q >> 3;
      v[e] = (__bf16)ldc[lane & 15][ks * 32 + (lane >> 4) * 8 + (q & 7)];
    }
    *(bf16x8*)(frag + (ks * 16 + f) * 512 + q0 + h * 8) = v;
  }
}

__global__ __launch_bounds__(256) void k0_prep(
    const float* __restrict__ ul_whh, const float* __restrict__ uavl_wih,
    const float* __restrict__ msg_w1, const float* __restrict__ msg_w2,
    const float* __restrict__ upd_w1, const float* __restrict__ upd_w2,
    const float* __restrict__ att_w,  const float* __restrict__ att_b,
    const float* __restrict__ wq_w,   const float* __restrict__ wq_b,
    const float* __restrict__ wr_w,   const float* __restrict__ wr_b,
    char* __restrict__ ws)
{
  const int b = blockIdx.x, t = threadIdx.x;
  if (b < 32) {
    const int dir = b >> 4, tile = b & 15;
    tile_transpose_perm(ul_whh + dir * 65536, 128,
                        (float*)(ws + OFF_WHHT) + dir * 65536, 512,
                        (tile >> 3) * 64, (tile & 7) * 64);
  } else if (b < 96) {
    const int b2 = b - 32, dir = b2 >> 5, tile = b2 & 31;
    tile_transpose_perm(uavl_wih + dir * 131072, 256,
                        (float*)(ws + OFF_WIHT) + dir * 131072, 512,
                        (tile >> 3) * 64, (tile & 7) * 64);
  } else if (b < 112) {
    frag_cast16<256>(msg_w2, (b - 96) * 16, (__bf16*)(ws + OFF_W2F));
  } else if (b < 128) {
    frag_cast16<512>(msg_w1, (b - 112) * 16, (__bf16*)(ws + OFF_W1F));
  } else if (b < 144) {
    frag_cast16<512>(upd_w1, (b - 128) * 16, (__bf16*)(ws + OFF_UW1F));
  } else if (b < 160) {
    frag_cast16<256>(upd_w2, (b - 144) * 16, (__bf16*)(ws + OFF_UW2F));
  } else {
    float* wqa = (float*)(ws + OFF_ATT);
    float* vv  = wqa + 256;
    float* c0  = wqa + 512;
    float sa = 0.f, sr = 0.f;
    for (int j = 0; j < 256; ++j) {
      sa += att_w[j]       * wq_w[j * 256 + t];
      sr += att_w[256 + j] * wr_w[j * 256 + t];
    }
    wqa[t] = sa; vv[t] = sr;
    __shared__ float red[256];
    red[t] = att_w[t] * wq_b[t] + att_w[256 + t] * wr_b[t];
    __syncthreads();
    for (int s = 128; s > 0; s >>= 1) { if (t < s) red[t] += red[t + s]; __syncthreads(); }
    if (t == 0) c0[0] = red[0] + att_b[0];
  }
}

// =====================================================================
// K1: user BiLSTM (4 users/block, coalesced frag stores) + UAV embed
// =====================================================================
__global__ __launch_bounds__(256) void k1_embed(
    const float* __restrict__ x, const float* __restrict__ ul_wih,
    const float* __restrict__ ul_b, const float* __restrict__ uav_lin_w,
    const float* __restrict__ uav_lin_b, char* __restrict__ ws)
{
  __bf16* huf = (__bf16*)(ws + OFF_HUF);
  const int b = blockIdx.x, tid = threadIdx.x;
  if (b < 256) {
    const float* whhT = (const float*)(ws + OFF_WHHT);
    const int dir = tid >> 7, hc = tid & 127;
    const int u0 = b * 4;
    float wx[4], wy[4], bb[4];
#pragma unroll
    for (int g = 0; g < 4; ++g) {
      int row = g * 128 + hc;
      wx[g] = ul_wih[dir * 1024 + row * 2 + 0];
      wy[g] = ul_wih[dir * 1024 + row * 2 + 1];
      bb[g] = ul_b[dir * 512 + row];
    }
    __shared__ float h1s[2][128][4];
    __shared__ float hout[8][260];
    float c1[4], h1v[4], in1x[4], in1y[4];
#pragma unroll
    for (int uu = 0; uu < 4; ++uu) {
      int u = u0 + uu;
      float ax = x[u * 2], ay = x[u * 2 + 1];
      float bx = x[(UQ + u) * 2], by = x[(UQ + u) * 2 + 1];
      float i0x = dir ? bx : ax, i0y = dir ? by : ay;
      in1x[uu] = dir ? ax : bx; in1y[uu] = dir ? ay : by;
      float gv[4];
#pragma unroll
      for (int g = 0; g < 4; ++g) gv[g] = wx[g] * i0x + wy[g] * i0y + bb[g];
      float ii = sigm(gv[0]), gg = tanhf(gv[2]), oo = sigm(gv[3]);
      c1[uu] = ii * gg;
      h1v[uu] = oo * tanhf(c1[uu]);
      h1s[dir][hc][uu] = h1v[uu];
    }
    __syncthreads();
    float acc[4][4];
#pragma unroll
    for (int uu = 0; uu < 4; ++uu)
#pragma unroll
      for (int g = 0; g < 4; ++g) acc[uu][g] = wx[g] * in1x[uu] + wy[g] * in1y[uu] + bb[g];
    for (int k = 0; k < 128; ++k) {
      f32x4 hv  = *(const f32x4*)&h1s[dir][k][0];
      f32x4 wv4 = *(const f32x4*)(whhT + dir * 65536 + k * 512 + hc * 4);
#pragma unroll
      for (int uu = 0; uu < 4; ++uu)
#pragma unroll
        for (int g = 0; g < 4; ++g) acc[uu][g] += hv[uu] * wv4[g];
    }
    const int col = dir * 128 + hc;
#pragma unroll
    for (int uu = 0; uu < 4; ++uu) {
      float ii = sigm(acc[uu][0]), ff = sigm(acc[uu][1]);
      float gg = tanhf(acc[uu][2]), oo = sigm(acc[uu][3]);
      float c2 = ff * c1[uu] + ii * gg;
      float h2v = oo * tanhf(c2);
      float va = dir ? h2v : h1v[uu];   // node u
      float vb = dir ? h1v[uu] : h2v;   // node UQ+u
      hout[uu][col] = va;
      hout[4 + uu][col] = vb;
    }
    __syncthreads();
    // coalesced frag-major store: thread -> (local row, 8-col chunk)
    {
      const int lr = tid >> 5, c = tid & 31;
      bf16x8 v;
#pragma unroll
      for (int e = 0; e < 8; ++e) v[e] = (__bf16)hout[lr][c * 8 + e];
      const int node = (lr < 4) ? (u0 + lr) : (UQ + u0 + lr - 4);
      *(bf16x8*)(huf + huf_idx(node, c * 8)) = v;
    }
  } else {
    float* hb = (float*)(ws + OFF_HB);
    const int j = tid;
    const int mb = (b - 256) * 16;
    for (int m = mb; m < mb + 16; ++m) {
      float xa = x[(NUQ + m) * 2], xb = x[(NUQ + m) * 2 + 1];
      float val = xa * uav_lin_w[j * 2] + xb * uav_lin_w[j * 2 + 1] + uav_lin_b[j];
      hb[m * 256 + j] = val;
      huf[huf_idx(NUQ + m, j)] = (__bf16)val;
    }
  }
}

// =====================================================================
// frag-major MFMA GEMM core: 4 waves (cg over cols), 64 rows x 256 cols
// =====================================================================
template<int NKS>
__device__ __forceinline__ void frag_gemm_acc(const __bf16* __restrict__ Abase,
                                              const __bf16* __restrict__ Bbase,
                                              f32x4 acc[4][4]) {
  const int lane = threadIdx.x & 63;
  const int cg = threadIdx.x >> 6;
  for (int ks = 0; ks < NKS; ++ks) {
    bf16x8 Af[4], Bf[4];
#pragma unroll
    for (int g = 0; g < 4; ++g)
      Af[g] = *(const bf16x8*)(Abase + ((ks * 4 + g) * 64 + lane) * 8);
#pragma unroll
    for (int f = 0; f < 4; ++f)
      Bf[f] = *(const bf16x8*)(Bbase + ((ks * 16 + cg * 4 + f) * 64 + lane) * 8);
#pragma unroll
    for (int g = 0; g < 4; ++g)
#pragma unroll
      for (int f = 0; f < 4; ++f)
        acc[g][f] = __builtin_amdgcn_mfma_f32_16x16x32_bf16(Af[g], Bf[f], acc[g][f], 0, 0, 0);
  }
}

// =====================================================================
// K2: P_user frag (32 blocks), P_uav+b1 (1), s'_m (1)
// =====================================================================
__global__ __launch_bounds__(256) void k2_proj(const float* __restrict__ msg_b1,
                                               char* __restrict__ ws)
{
  const __bf16* huf = (const __bf16*)(ws + OFF_HUF);
  const __bf16* w1f = (const __bf16*)(ws + OFF_W1F);
  const int b = blockIdx.x;
  const int lane = threadIdx.x & 63, cg = threadIdx.x >> 6;
  const int cl = lane & 15, g16 = lane >> 4;
  if (b < 32) {
    f32x4 acc[4][4] = {};
    frag_gemm_acc<8>(huf + b * 16384, w1f + 65536, acc);
    __bf16* pubf = (__bf16*)(ws + OFF_PUBF);
#pragma unroll
    for (int g = 0; g < 4; ++g)
#pragma unroll
      for (int f = 0; f < 4; ++f)
#pragma unroll
        for (int r = 0; r < 4; ++r) {
          int row = b * 64 + g * 16 + g16 * 4 + r;
          int col = cg * 64 + f * 16 + cl;
          pubf[pubf_idx(row, col)] = (__bf16)acc[g][f][r];
        }
  } else if (b == 32) {
    f32x4 acc[4][4] = {};
    frag_gemm_acc<8>(huf + 32 * 16384, w1f, acc);
    float* pb = (float*)(ws + OFF_PB);
#pragma unroll
    for (int g = 0; g < 4; ++g)
#pragma unroll
      for (int f = 0; f < 4; ++f)
#pragma unroll
        for (int r = 0; r < 4; ++r) {
          int row = g * 16 + g16 * 4 + r;
          int col = cg * 64 + f * 16 + cl;
          pb[row * 256 + col] = acc[g][f][r] + msg_b1[col];
        }
  } else {
    const float* hb  = (const float*)(ws + OFF_HB);
    const float* wqa = (const float*)(ws + OFF_ATT);
    const float* c0  = wqa + 512;
    float* spr = (float*)(ws + OFF_SPR);
    const int t = threadIdx.x;
    if (t < 64) {
      float s = 0.f;
      for (int k = 0; k < 256; ++k) s += hb[t * 256 + k] * wqa[k];
      spr[t] = s + c0[0];
    }
  }
}

// =====================================================================
// K3: edge msg layer-2 + attention + chunk softmax.
// 16 waves (4rg x 4cg). Staging-time repack: each wave loads its raw
// A-frag global->reg, adds PB + relu + bf16 ONCE, ds_writes; consume
// phase is pure ds_read+MFMA (4x less repack VALU than R3).
// =====================================================================
__global__ __launch_bounds__(1024, 2) void k3_edge(const float* __restrict__ msg_b2,
                                                   char* __restrict__ ws)
{
  const char*  PUBF = (const char*)(ws + OFF_PUBF);
  const float* PB   = (const float*)(ws + OFF_PB);
  const float* spr  = (const float*)(ws + OFF_SPR);
  const float* vv   = (const float*)(ws + OFF_ATT) + 256;
  const char*  W2F  = (const char*)(ws + OFF_W2F);
  float* crec = (float*)(ws + OFF_CREC);

  __shared__ __align__(16) char bufA[2][16384];
  __shared__ __align__(16) char bufB[2][16384];
  __shared__ float plds[16][64];
  __shared__ float redmax[16], wds[16];
  __shared__ float wvs[4][256];

  const int m = blockIdx.x >> 3, ch = blockIdx.x & 7;
  const int tid = threadIdx.x, wave = tid >> 6, lane = tid & 63;
  const int cl = lane & 15, g16 = lane >> 4;
  const int rg = wave >> 2, cg = wave & 3;
  const float sm = spr[m];
  const char* Asrc = PUBF + ch * 131072;
  const float* pbm = PB + m * 256;

  // prologue: stage ks=0 (repack A in regs, gl16 B)
  {
    bf16x8 araw = *(const bf16x8*)(Asrc + wave * 1024 + lane * 16);
    gl16(W2F + wave * 1024 + lane * 16, &bufB[0][wave * 1024]);
    const float* pbp = pbm + (lane >> 4) * 8;
    f32x4 p0 = *(const f32x4*)pbp, p1 = *(const f32x4*)(pbp + 4);
    bf16x8 a;
#pragma unroll
    for (int r = 0; r < 4; ++r) {
      a[r]     = (__bf16)fmaxf((float)araw[r]     + p0[r], 0.f);
      a[4 + r] = (__bf16)fmaxf((float)araw[4 + r] + p1[r], 0.f);
    }
    *(bf16x8*)(&bufA[0][wave * 1024 + lane * 16]) = a;
  }
  __syncthreads();

  f32x4 acc[4][4] = {};
  for (int ks = 0; ks < 8; ++ks) {
    const int cur = ks & 1;
    bf16x8 arn{};
    f32x4 pn0{}, pn1{};
    if (ks < 7) {
      arn = *(const bf16x8*)(Asrc + (ks + 1) * 16384 + wave * 1024 + lane * 16);
      gl16(W2F + (ks + 1) * 16384 + wave * 1024 + lane * 16, &bufB[cur ^ 1][wave * 1024]);
      const float* pbp = pbm + (ks + 1) * 32 + (lane >> 4) * 8;
      pn0 = *(const f32x4*)pbp;
      pn1 = *(const f32x4*)(pbp + 4);
    }
    bf16x8 Af[4], Bf[4];
#pragma unroll
    for (int g = 0; g < 4; ++g)
      Af[g] = *(const bf16x8*)(&bufA[cur][((rg * 4 + g) * 64 + lane) * 16]);
#pragma unroll
    for (int f = 0; f < 4; ++f)
      Bf[f] = *(const bf16x8*)(&bufB[cur][((cg * 4 + f) * 64 + lane) * 16]);
#pragma unroll
    for (int g = 0; g < 4; ++g)
#pragma unroll
      for (int f = 0; f < 4; ++f)
        acc[g][f] = __builtin_amdgcn_mfma_f32_16x16x32_bf16(Af[g], Bf[f], acc[g][f], 0, 0, 0);
    if (ks < 7) {
      bf16x8 a;
#pragma unroll
      for (int r = 0; r < 4; ++r) {
        a[r]     = (__bf16)fmaxf((float)arn[r]     + pn0[r], 0.f);
        a[4 + r] = (__bf16)fmaxf((float)arn[4 + r] + pn1[r], 0.f);
      }
      *(bf16x8*)(&bufA[cur ^ 1][wave * 1024 + lane * 16]) = a;
    }
    __syncthreads();
  }

  // msg = relu(acc + b2); logit partial over this wave's 64 cols
  float p[4][4] = {};
#pragma unroll
  for (int f = 0; f < 4; ++f) {
    const int j = cg * 64 + f * 16 + cl;
    const float b2j = msg_b2[j], vj = vv[j];
#pragma unroll
    for (int g = 0; g < 4; ++g)
#pragma unroll
      for (int r = 0; r < 4; ++r) {
        float mv = fmaxf(acc[g][f][r] + b2j, 0.f);
        acc[g][f][r] = mv;
        p[g][r] += mv * vj;
      }
  }
#pragma unroll
  for (int mask = 1; mask < 16; mask <<= 1)
#pragma unroll
    for (int g = 0; g < 4; ++g)
#pragma unroll
      for (int r = 0; r < 4; ++r) p[g][r] += __shfl_xor(p[g][r], mask);
  if (cl == 0) {
#pragma unroll
    for (int g = 0; g < 4; ++g)
#pragma unroll
      for (int r = 0; r < 4; ++r) plds[wave][g * 16 + g16 * 4 + r] = p[g][r];
  }
  __syncthreads();

  float lr[4][4], wm = -3.4e38f;
#pragma unroll
  for (int g = 0; g < 4; ++g)
#pragma unroll
    for (int r = 0; r < 4; ++r) {
      int row = g * 16 + g16 * 4 + r;
      float l = plds[rg * 4 + 0][row] + plds[rg * 4 + 1][row] +
                plds[rg * 4 + 2][row] + plds[rg * 4 + 3][row] + sm;
      l = l > 0.f ? l : 0.2f * l;
      lr[g][r] = l;
      wm = fmaxf(wm, l);
    }
  wm = fmaxf(wm, __shfl_xor(wm, 16));
  wm = fmaxf(wm, __shfl_xor(wm, 32));
  if (lane == 0) redmax[wave] = wm;
  __syncthreads();
  float Mc = redmax[0];
#pragma unroll
  for (int i = 1; i < 16; ++i) Mc = fmaxf(Mc, redmax[i]);

  float e[4][4], ds = 0.f;
#pragma unroll
  for (int g = 0; g < 4; ++g)
#pragma unroll
    for (int r = 0; r < 4; ++r) { e[g][r] = __expf(lr[g][r] - Mc); ds += e[g][r]; }
  ds += __shfl_xor(ds, 16);
  ds += __shfl_xor(ds, 32);
  if (lane == 0) wds[wave] = ds;

#pragma unroll
  for (int f = 0; f < 4; ++f) {
    float w = 0.f;
#pragma unroll
    for (int g = 0; g < 4; ++g)
#pragma unroll
      for (int r = 0; r < 4; ++r) w += e[g][r] * acc[g][f][r];
    w += __shfl_xor(w, 16);
    w += __shfl_xor(w, 32);
    if (g16 == 0) wvs[rg][cg * 64 + f * 16 + cl] = w;
  }
  __syncthreads();

  float* rec = crec + (m * 8 + ch) * 260;
  if (tid < 256) rec[tid] = wvs[0][tid] + wvs[1][tid] + wvs[2][tid] + wvs[3][tid];
  if (tid == 0) rec[256] = Mc;
  if (tid == 1) rec[257] = wds[0] + wds[4] + wds[8] + wds[12];
}

// =====================================================================
// K56: fused update MLP (layer1 -> LDS -> layer2) + user lin2+sigmoid.
// blocks 0..31: user rows (agg==0 -> h-half GEMM only), fused output.
// block 32: agg combine (k4) in-LDS + UAV rows, writes H2U.
// =====================================================================
__global__ __launch_bounds__(256) void k56_update(
    const float* __restrict__ upd_b1, const float* __restrict__ upd_b2,
    const float* __restrict__ lin2_w, const float* __restrict__ lin2_b,
    float* __restrict__ out, char* __restrict__ ws)
{
  const __bf16* huf  = (const __bf16*)(ws + OFF_HUF);
  const __bf16* uw1f = (const __bf16*)(ws + OFF_UW1F);
  const __bf16* uw2f = (const __bf16*)(ws + OFF_UW2F);

  __shared__ __align__(16) __bf16 l1f[8 * 4 * 512];   // 32 KB layer1 frag
  __shared__ __align__(16) __bf16 aggf[8 * 4 * 512];  // 32 KB UAV A (agg half)
  __shared__ float scs[64][8];
  __shared__ float sS[64];
  __shared__ float l2p[4][64][2];

  const int b = blockIdx.x, tid = threadIdx.x;
  const int lane = tid & 63, cg = tid >> 6;
  const int cl = lane & 15, g16 = lane >> 4;

  f32x4 acc[4][4] = {};
  if (b < 32) {
    // users: layer1 = relu(h @ W1b^T + b1)
    frag_gemm_acc<8>(huf + b * 16384, uw1f + 8 * 16 * 512, acc);
  } else {
    // ---- agg combine (k4) ----
    const float* crec = (const float*)(ws + OFF_CREC);
    if (tid < 64) {
      const int m = tid;
      float mx = -3.4e38f;
      for (int c = 0; c < 8; ++c) mx = fmaxf(mx, crec[(m * 8 + c) * 260 + 256]);
      float S = 0.f;
      for (int c = 0; c < 8; ++c) {
        float sc = __expf(crec[(m * 8 + c) * 260 + 256] - mx);
        scs[m][c] = sc;
        S += sc * crec[(m * 8 + c) * 260 + 257];
      }
      sS[m] = S;
    }
    __syncthreads();
    for (int m = 0; m < 64; ++m) {
      float A = 0.f;
#pragma unroll
      for (int c = 0; c < 8; ++c) A += scs[m][c] * crec[(m * 8 + c) * 260 + tid];
      float agg = A / sS[m] * (1.f / 2048.f);
      aggf[((tid >> 5) * 4 + (m >> 4)) * 512 + (((tid >> 3) & 3) * 16 + (m & 15)) * 8 + (tid & 7)] =
          (__bf16)agg;
    }
    __syncthreads();
    // ---- layer1 UAV: ks 0..7 from aggf (LDS), ks 8..15 from huf ----
    const __bf16* hufu = huf + 32 * 16384;
    for (int ks = 0; ks < 8; ++ks) {
      bf16x8 Af[4], Bf[4];
#pragma unroll
      for (int g = 0; g < 4; ++g)
        Af[g] = *(const bf16x8*)(aggf + ((ks * 4 + g) * 64 + lane) * 8);
#pragma unroll
      for (int f = 0; f < 4; ++f)
        Bf[f] = *(const bf16x8*)(uw1f + ((ks * 16 + cg * 4 + f) * 64 + lane) * 8);
#pragma unroll
      for (int g = 0; g < 4; ++g)
#pragma unroll
        for (int f = 0; f < 4; ++f)
          acc[g][f] = __builtin_amdgcn_mfma_f32_16x16x32_bf16(Af[g], Bf[f], acc[g][f], 0, 0, 0);
    }
    for (int ks = 8; ks < 16; ++ks) {
      bf16x8 Af[4], Bf[4];
#pragma unroll
      for (int g = 0; g < 4; ++g)
        Af[g] = *(const bf16x8*)(hufu + (((ks - 8) * 4 + g) * 64 + lane) * 8);
#pragma unroll
      for (int f = 0; f < 4; ++f)
        Bf[f] = *(const bf16x8*)(uw1f + ((ks * 16 + cg * 4 + f) * 64 + lane) * 8);
#pragma unroll
      for (int g = 0; g < 4; ++g)
#pragma unroll
        for (int f = 0; f < 4; ++f)
          acc[g][f] = __builtin_amdgcn_mfma_f32_16x16x32_bf16(Af[g], Bf[f], acc[g][f], 0, 0, 0);
    }
  }

  // bias + relu -> l1f (frag-major in LDS)
#pragma unroll
  for (int g = 0; g < 4; ++g)
#pragma unroll
    for (int f = 0; f < 4; ++f) {
      const int col = cg * 64 + f * 16 + cl;
      const float b1 = upd_b1[col];
#pragma unroll
      for (int r = 0; r < 4; ++r) {
        const int rl = g * 16 + g16 * 4 + r;
        float v = fmaxf(acc[g][f][r] + b1, 0.f);
        l1f[((col >> 5) * 4 + g) * 512 + (((col >> 3) & 3) * 16 + (rl & 15)) * 8 + (col & 7)] =
            (__bf16)v;
      }
    }
  __syncthreads();

  // layer2
  f32x4 a2[4][4] = {};
  for (int ks = 0; ks < 8; ++ks) {
    bf16x8 Af[4], Bf[4];
#pragma unroll
    for (int g = 0; g < 4; ++g)
      Af[g] = *(const bf16x8*)(l1f + ((ks * 4 + g) * 64 + lane) * 8);
#pragma unroll
    for (int f = 0; f < 4; ++f)
      Bf[f] = *(const bf16x8*)(uw2f + ((ks * 16 + cg * 4 + f) * 64 + lane) * 8);
#pragma unroll
    for (int g = 0; g < 4; ++g)
#pragma unroll
      for (int f = 0; f < 4; ++f)
        a2[g][f] = __builtin_amdgcn_mfma_f32_16x16x32_bf16(Af[g], Bf[f], a2[g][f], 0, 0, 0);
  }

  if (b < 32) {
    // fused lin2 + sigmoid for 64 user rows
    float d0[4][4] = {}, d1[4][4] = {};
#pragma unroll
    for (int f = 0; f < 4; ++f) {
      const int col = cg * 64 + f * 16 + cl;
      const float b2 = upd_b2[col];
      const float w0 = lin2_w[col], w1 = lin2_w[256 + col];
#pragma unroll
      for (int g = 0; g < 4; ++g)
#pragma unroll
        for (int r = 0; r < 4; ++r) {
          float hv = fmaxf(a2[g][f][r] + b2, 0.f);
          d0[g][r] += hv * w0;
          d1[g][r] += hv * w1;
        }
    }
#pragma unroll
    for (int mask = 1; mask < 16; mask <<= 1)
#pragma unroll
      for (int g = 0; g < 4; ++g)
#pragma unroll
        for (int r = 0; r < 4; ++r) {
          d0[g][r] += __shfl_xor(d0[g][r], mask);
          d1[g][r] += __shfl_xor(d1[g][r], mask);
        }
    if (cl == 0) {
#pragma unroll
      for (int g = 0; g < 4; ++g)
#pragma unroll
        for (int r = 0; r < 4; ++r) {
          l2p[cg][g * 16 + g16 * 4 + r][0] = d0[g][r];
          l2p[cg][g * 16 + g16 * 4 + r][1] = d1[g][r];
        }
    }
    __syncthreads();
    if (tid < 64) {
      float s0 = l2p[0][tid][0] + l2p[1][tid][0] + l2p[2][tid][0] + l2p[3][tid][0] + lin2_b[0];
      float s1 = l2p[0][tid][1] + l2p[1][tid][1] + l2p[2][tid][1] + l2p[3][tid][1] + lin2_b[1];
      const int row = b * 64 + tid;
      out[row * 2 + 0] = 1.f / (1.f + expf(-s0));
      out[row * 2 + 1] = 1.f / (1.f + expf(-s1));
    }
  } else {
    float* h2u = (float*)(ws + OFF_H2U);
#pragma unroll
    for (int g = 0; g < 4; ++g)
#pragma unroll
      for (int f = 0; f < 4; ++f) {
        const int col = cg * 64 + f * 16 + cl;
        const float b2 = upd_b2[col];
#pragma unroll
        for (int r = 0; r < 4; ++r) {
          const int rl = g * 16 + g16 * 4 + r;
          h2u[rl * 256 + col] = fmaxf(a2[g][f][r] + b2, 0.f);
        }
      }
  }
}

// =====================================================================
// K7: UAV BiLSTM (T=1) + final linear + sigmoid (UAV rows only)
// =====================================================================
__global__ __launch_bounds__(256) void k7_final(
    const float* __restrict__ uavl_b, const float* __restrict__ lin2_w,
    const float* __restrict__ lin2_b, float* __restrict__ out, char* __restrict__ ws)
{
  const float* h2u = (const float*)(ws + OFF_H2U);
  const int b = blockIdx.x, tid = threadIdx.x;
  const float* wihT = (const float*)(ws + OFF_WIHT);
  __shared__ float xs[256], uo[256];
  xs[tid] = h2u[b * 256 + tid];
  __syncthreads();
  const int dir = tid >> 7, hc = tid & 127;
  float a4[4] = {0.f, 0.f, 0.f, 0.f};
  for (int k = 0; k < 256; ++k) {
    float xv = xs[k];
    f32x4 wv4 = *(const f32x4*)(wihT + dir * 131072 + k * 512 + hc * 4);
#pragma unroll
    for (int g = 0; g < 4; ++g) a4[g] += xv * wv4[g];
  }
  float bb[4];
#pragma unroll
  for (int g = 0; g < 4; ++g) bb[g] = uavl_b[dir * 512 + g * 128 + hc];
  float ii = sigm(a4[0] + bb[0]);
  float gg = tanhf(a4[2] + bb[2]);
  float oo = sigm(a4[3] + bb[3]);
  float cc = ii * gg;
  uo[dir * 128 + hc] = oo * tanhf(cc);
  __syncthreads();
  float p0 = uo[tid] * lin2_w[tid];
  float p1 = uo[tid] * lin2_w[256 + tid];
#pragma unroll
  for (int mask = 1; mask < 64; mask <<= 1) {
    p0 += __shfl_xor(p0, mask);
    p1 += __shfl_xor(p1, mask);
  }
  __shared__ float r0s[4], r1s[4];
  const int lane = tid & 63, wv = tid >> 6;
  if (lane == 0) { r0s[wv] = p0; r1s[wv] = p1; }
  __syncthreads();
  if (tid == 0) {
    float d0 = r0s[0] + r0s[1] + r0s[2] + r0s[3] + lin2_b[0];
    float d1 = r1s[0] + r1s[1] + r1s[2] + r1s[3] + lin2_b[1];
    out[(NUQ + b) * 2 + 0] = 1.f / (1.f + expf(-d0));
    out[(NUQ + b) * 2 + 1] = 1.f / (1.f + expf(-d1));
  }
}

// =====================================================================
extern "C" void kernel_launch(void* const* d_in, const int* in_sizes, int n_in,
                              void* d_out, int out_size, void* d_ws, size_t ws_size,
                              hipStream_t stream)
{
  const float* x         = (const float*)d_in[0];
  const float* ul_wih    = (const float*)d_in[3];
  const float* ul_whh    = (const float*)d_in[4];
  const float* ul_b      = (const float*)d_in[5];
  const float* uav_lin_w = (const float*)d_in[6];
  const float* uav_lin_b = (const float*)d_in[7];
  const float* msg_w1    = (const float*)d_in[8];
  const float* msg_b1    = (const float*)d_in[9];
  const float* msg_w2    = (const float*)d_in[10];
  const float* msg_b2    = (const float*)d_in[11];
  const float* wq_w      = (const float*)d_in[12];
  const float* wq_b      = (const float*)d_in[13];
  const float* wr_w      = (const float*)d_in[14];
  const float* wr_b      = (const float*)d_in[15];
  const float* att_w     = (const float*)d_in[16];
  const float* att_b     = (const float*)d_in[17];
  const float* upd_w1    = (const float*)d_in[18];
  const float* upd_b1    = (const float*)d_in[19];
  const float* upd_w2    = (const float*)d_in[20];
  const float* upd_b2    = (const float*)d_in[21];
  const float* uavl_wih  = (const float*)d_in[22];
  const float* uavl_b    = (const float*)d_in[24];
  const float* lin2_w    = (const float*)d_in[25];
  const float* lin2_b    = (const float*)d_in[26];
  char* ws = (char*)d_ws;
  float* out = (float*)d_out;

  k0_prep<<<dim3(161), dim3(256), 0, stream>>>(ul_whh, uavl_wih, msg_w1, msg_w2, upd_w1,
                                               upd_w2, att_w, att_b, wq_w, wq_b, wr_w, wr_b, ws);
  k1_embed<<<dim3(260), dim3(256), 0, stream>>>(x, ul_wih, ul_b, uav_lin_w, uav_lin_b, ws);
  k2_proj<<<dim3(34), dim3(256), 0, stream>>>(msg_b1, ws);
  k3_edge<<<dim3(512), dim3(1024), 0, stream>>>(msg_b2, ws);
  k56_update<<<dim3(33), dim3(256), 0, stream>>>(upd_b1, upd_b2, lin2_w, lin2_b, out, ws);
  k7_final<<<dim3(64), dim3(256), 0, stream>>>(uavl_b, lin2_w, lin2_b, out, ws);
}

// Round 5
// 94.509 us; speedup vs baseline: 2.4903x; 1.1728x over previous
//
#include <hip/hip_runtime.h>
#include <hip/hip_bf16.h>
#include <math.h>

#define UQ   1024
#define NUQ  2048
#define MQ   64
#define NN   2112
#define HD   256

typedef __attribute__((ext_vector_type(4))) float f32x4;
typedef __attribute__((ext_vector_type(8))) __bf16 bf16x8;

// ---- workspace layout (bytes) ----
#define OFF_HB    0u          // UAV h f32 [64][256]                65,536
#define OFF_HUF   65536u      // h frag bf16 [33][8][4][512]     1,081,344
#define OFF_PUBF  1146880u    // P_user frag bf16 [8][8][16][512]1,048,576
#define OFF_PB    2195456u    // P_uav+b1 f32 [64][256]             65,536
#define OFF_SPR   2260992u    // s'_m f32 [64]                         256
#define OFF_ATT   2261248u    // wqa[256], v[256], const0            2,304
#define OFF_WHHT  2263552u    // user WhhT2 f32 [2][128][512]      524,288
#define OFF_WIHT  2787840u    // uav WihT2 f32 [2][256][512]     1,048,576
#define OFF_W1F   3836416u    // msg_w1 frag bf16 [16][16][512]    262,144
#define OFF_W2F   4098560u    // msg_w2 frag bf16 [8][16][512]     131,072
#define OFF_UW1F  4229632u    // upd_w1 frag bf16 [16][16][512]    262,144
#define OFF_UW2F  4491776u    // upd_w2 frag bf16 [8][16][512]     131,072
#define OFF_CREC  4622848u    // chunk rec f32 [512][260]          532,480
#define OFF_H2U   5155328u    // h2 UAV f32 [64][256]               65,536
#define OFF_PART  5220864u    // uav-lstm gate partials [64][4][1024] f32 1,048,576
// total ~6.3 MB

__device__ __forceinline__ float sigm(float v) { return 1.f / (1.f + expf(-v)); }

// fragment-major index helpers: element (row, k)
__device__ __forceinline__ int huf_idx(int row, int k) {   // [33][8][4][512]
  return (((row >> 6) * 8 + (k >> 5)) * 4 + ((row >> 4) & 3)) * 512 +
         (((k >> 3) & 3) * 16 + (row & 15)) * 8 + (k & 7);
}
__device__ __forceinline__ int pubf_idx(int row, int k) {  // [8][8][16][512]
  return (((row >> 8) * 8 + (k >> 5)) * 16 + ((row >> 4) & 15)) * 512 +
         (((k >> 3) & 3) * 16 + (row & 15)) * 8 + (k & 7);
}

__device__ __forceinline__ void gl16(const void* g, void* l) {
  __builtin_amdgcn_global_load_lds((const __attribute__((address_space(1))) void*)g,
                                   (__attribute__((address_space(3))) void*)l, 16, 0, 0);
}

// =====================================================================
// K0: weight preprocessing — LDS-tiled transposes + fragment-major casts
// =====================================================================
__device__ void tile_transpose_perm(const float* __restrict__ in, int in_ld,
                                    float* __restrict__ out, int out_ld,
                                    int k0, int c0) {
  __shared__ float ldt[64][68];
  const int t = threadIdx.x;
  {
    const int ci = t >> 2, kq = t & 3;
    const int c = c0 + ci;
    const int row = (c & 3) * 128 + (c >> 2);
    const float* src = in + row * in_ld + k0 + kq * 16;
#pragma unroll
    for (int e = 0; e < 4; ++e)
      *(f32x4*)&ldt[ci][kq * 16 + e * 4] = *(const f32x4*)(src + e * 4);
  }
  __syncthreads();
  {
    const int kk = t >> 2, cq = t & 3;
    float* dst = out + (k0 + kk) * out_ld + c0 + cq * 16;
#pragma unroll
    for (int e4 = 0; e4 < 4; ++e4) {
      f32x4 v;
#pragma unroll
      for (int j = 0; j < 4; ++j) v[j] = ldt[cq * 16 + e4 * 4 + j][kk];
      *(f32x4*)(dst + e4 * 4) = v;
    }
  }
}

template<int K>
__device__ void frag_cast16(const float* __restrict__ W, int j0, __bf16* __restrict__ frag) {
  __shared__ float ldc[16][K + 4];
  const int t = threadIdx.x;
  {
    const int jr = t >> 4, kq = t & 15;
    const float* src = W + (j0 + jr) * K + kq * (K / 16);
#pragma unroll
    for (int e = 0; e < K / 64; ++e)
      *(f32x4*)&ldc[jr][kq * (K / 16) + e * 4] = *(const f32x4*)(src + e * 4);
  }
  __syncthreads();
  const int f = j0 >> 4;
  constexpr int nks = K >> 5;
  constexpr int thr_per_ks = 256 / nks;
  constexpr int q_per_thr = 512 / thr_per_ks;
  const int ks = t / thr_per_ks;
  const int q0 = (t % thr_per_ks) * q_per_thr;
#pragma unroll
  for (int h = 0; h < q_per_thr / 8; ++h) {
    bf16x8 v;
#pragma unroll
    for (int e = 0; e < 8; ++e) {
      int q = q0 + h * 8 + e;
      int lane = q >> 3;
      v[e] = (__bf16)ldc[lane & 15][ks * 32 + (lane >> 4) * 8 + (q & 7)];
    }
    *(bf16x8*)(frag + (ks * 16 + f) * 512 + q0 + h * 8) = v;
  }
}

__global__ __launch_bounds__(256) void k0_prep(
    const float* __restrict__ ul_whh, const float* __restrict__ uavl_wih,
    const float* __restrict__ msg_w1, const float* __restrict__ msg_w2,
    const float* __restrict__ upd_w1, const float* __restrict__ upd_w2,
    const float* __restrict__ att_w,  const float* __restrict__ att_b,
    const float* __restrict__ wq_w,   const float* __restrict__ wq_b,
    const float* __restrict__ wr_w,   const float* __restrict__ wr_b,
    char* __restrict__ ws)
{
  const int b = blockIdx.x, t = threadIdx.x;
  if (b < 32) {
    const int dir = b >> 4, tile = b & 15;
    tile_transpose_perm(ul_whh + dir * 65536, 128,
                        (float*)(ws + OFF_WHHT) + dir * 65536, 512,
                        (tile >> 3) * 64, (tile & 7) * 64);
  } else if (b < 96) {
    const int b2 = b - 32, dir = b2 >> 5, tile = b2 & 31;
    tile_transpose_perm(uavl_wih + dir * 131072, 256,
                        (float*)(ws + OFF_WIHT) + dir * 131072, 512,
                        (tile >> 3) * 64, (tile & 7) * 64);
  } else if (b < 112) {
    frag_cast16<256>(msg_w2, (b - 96) * 16, (__bf16*)(ws + OFF_W2F));
  } else if (b < 128) {
    frag_cast16<512>(msg_w1, (b - 112) * 16, (__bf16*)(ws + OFF_W1F));
  } else if (b < 144) {
    frag_cast16<512>(upd_w1, (b - 128) * 16, (__bf16*)(ws + OFF_UW1F));
  } else if (b < 160) {
    frag_cast16<256>(upd_w2, (b - 144) * 16, (__bf16*)(ws + OFF_UW2F));
  } else {
    float* wqa = (float*)(ws + OFF_ATT);
    float* vv  = wqa + 256;
    float* c0  = wqa + 512;
    float sa = 0.f, sr = 0.f;
    for (int j = 0; j < 256; ++j) {
      sa += att_w[j]       * wq_w[j * 256 + t];
      sr += att_w[256 + j] * wr_w[j * 256 + t];
    }
    wqa[t] = sa; vv[t] = sr;
    __shared__ float red[256];
    red[t] = att_w[t] * wq_b[t] + att_w[256 + t] * wr_b[t];
    __syncthreads();
    for (int s = 128; s > 0; s >>= 1) { if (t < s) red[t] += red[t + s]; __syncthreads(); }
    if (t == 0) c0[0] = red[0] + att_b[0];
  }
}

// =====================================================================
// K1: user BiLSTM (4 users/block, coalesced frag stores) + UAV embed
// =====================================================================
__global__ __launch_bounds__(256) void k1_embed(
    const float* __restrict__ x, const float* __restrict__ ul_wih,
    const float* __restrict__ ul_b, const float* __restrict__ uav_lin_w,
    const float* __restrict__ uav_lin_b, char* __restrict__ ws)
{
  __bf16* huf = (__bf16*)(ws + OFF_HUF);
  const int b = blockIdx.x, tid = threadIdx.x;
  if (b < 256) {
    const float* whhT = (const float*)(ws + OFF_WHHT);
    const int dir = tid >> 7, hc = tid & 127;
    const int u0 = b * 4;
    float wx[4], wy[4], bb[4];
#pragma unroll
    for (int g = 0; g < 4; ++g) {
      int row = g * 128 + hc;
      wx[g] = ul_wih[dir * 1024 + row * 2 + 0];
      wy[g] = ul_wih[dir * 1024 + row * 2 + 1];
      bb[g] = ul_b[dir * 512 + row];
    }
    __shared__ float h1s[2][128][4];
    __shared__ float hout[8][260];
    float c1[4], h1v[4], in1x[4], in1y[4];
#pragma unroll
    for (int uu = 0; uu < 4; ++uu) {
      int u = u0 + uu;
      float ax = x[u * 2], ay = x[u * 2 + 1];
      float bx = x[(UQ + u) * 2], by = x[(UQ + u) * 2 + 1];
      float i0x = dir ? bx : ax, i0y = dir ? by : ay;
      in1x[uu] = dir ? ax : bx; in1y[uu] = dir ? ay : by;
      float gv[4];
#pragma unroll
      for (int g = 0; g < 4; ++g) gv[g] = wx[g] * i0x + wy[g] * i0y + bb[g];
      float ii = sigm(gv[0]), gg = tanhf(gv[2]), oo = sigm(gv[3]);
      c1[uu] = ii * gg;
      h1v[uu] = oo * tanhf(c1[uu]);
      h1s[dir][hc][uu] = h1v[uu];
    }
    __syncthreads();
    float acc[4][4];
#pragma unroll
    for (int uu = 0; uu < 4; ++uu)
#pragma unroll
      for (int g = 0; g < 4; ++g) acc[uu][g] = wx[g] * in1x[uu] + wy[g] * in1y[uu] + bb[g];
    for (int k = 0; k < 128; ++k) {
      f32x4 hv  = *(const f32x4*)&h1s[dir][k][0];
      f32x4 wv4 = *(const f32x4*)(whhT + dir * 65536 + k * 512 + hc * 4);
#pragma unroll
      for (int uu = 0; uu < 4; ++uu)
#pragma unroll
        for (int g = 0; g < 4; ++g) acc[uu][g] += hv[uu] * wv4[g];
    }
    const int col = dir * 128 + hc;
#pragma unroll
    for (int uu = 0; uu < 4; ++uu) {
      float ii = sigm(acc[uu][0]), ff = sigm(acc[uu][1]);
      float gg = tanhf(acc[uu][2]), oo = sigm(acc[uu][3]);
      float c2 = ff * c1[uu] + ii * gg;
      float h2v = oo * tanhf(c2);
      float va = dir ? h2v : h1v[uu];   // node u
      float vb = dir ? h1v[uu] : h2v;   // node UQ+u
      hout[uu][col] = va;
      hout[4 + uu][col] = vb;
    }
    __syncthreads();
    {
      const int lr = tid >> 5, c = tid & 31;
      bf16x8 v;
#pragma unroll
      for (int e = 0; e < 8; ++e) v[e] = (__bf16)hout[lr][c * 8 + e];
      const int node = (lr < 4) ? (u0 + lr) : (UQ + u0 + lr - 4);
      *(bf16x8*)(huf + huf_idx(node, c * 8)) = v;
    }
  } else {
    float* hb = (float*)(ws + OFF_HB);
    const int j = tid;
    const int mb = (b - 256) * 16;
    for (int m = mb; m < mb + 16; ++m) {
      float xa = x[(NUQ + m) * 2], xb = x[(NUQ + m) * 2 + 1];
      float val = xa * uav_lin_w[j * 2] + xb * uav_lin_w[j * 2 + 1] + uav_lin_b[j];
      hb[m * 256 + j] = val;
      huf[huf_idx(NUQ + m, j)] = (__bf16)val;
    }
  }
}

// =====================================================================
// frag-major MFMA GEMM core: 4 waves (cg over 64-col groups), G*16 rows
// =====================================================================
template<int G, int NKS>
__device__ __forceinline__ void frag_gemm_acc_g(const __bf16* __restrict__ Abase, int g0,
                                                const __bf16* __restrict__ Bbase,
                                                f32x4 acc[G][4]) {
  const int lane = threadIdx.x & 63;
  const int cg = threadIdx.x >> 6;
  for (int ks = 0; ks < NKS; ++ks) {
    bf16x8 Af[G], Bf[4];
#pragma unroll
    for (int g = 0; g < G; ++g)
      Af[g] = *(const bf16x8*)(Abase + ((ks * 4 + g0 + g) * 64 + lane) * 8);
#pragma unroll
    for (int f = 0; f < 4; ++f)
      Bf[f] = *(const bf16x8*)(Bbase + ((ks * 16 + cg * 4 + f) * 64 + lane) * 8);
#pragma unroll
    for (int g = 0; g < G; ++g)
#pragma unroll
      for (int f = 0; f < 4; ++f)
        acc[g][f] = __builtin_amdgcn_mfma_f32_16x16x32_bf16(Af[g], Bf[f], acc[g][f], 0, 0, 0);
  }
}

// =====================================================================
// K2: P_user frag (64 x 32-row blocks), P_uav+b1 (1), s'_m (1)
// =====================================================================
__global__ __launch_bounds__(256) void k2_proj(const float* __restrict__ msg_b1,
                                               char* __restrict__ ws)
{
  const __bf16* huf = (const __bf16*)(ws + OFF_HUF);
  const __bf16* w1f = (const __bf16*)(ws + OFF_W1F);
  const int b = blockIdx.x;
  const int lane = threadIdx.x & 63, cg = threadIdx.x >> 6;
  const int cl = lane & 15, g16 = lane >> 4;
  if (b < 64) {
    f32x4 acc[2][4] = {};
    frag_gemm_acc_g<2, 8>(huf + (b >> 1) * 16384, (b & 1) * 2, w1f + 65536, acc);
    __bf16* pubf = (__bf16*)(ws + OFF_PUBF);
#pragma unroll
    for (int g = 0; g < 2; ++g)
#pragma unroll
      for (int f = 0; f < 4; ++f)
#pragma unroll
        for (int r = 0; r < 4; ++r) {
          int row = b * 32 + g * 16 + g16 * 4 + r;
          int col = cg * 64 + f * 16 + cl;
          pubf[pubf_idx(row, col)] = (__bf16)acc[g][f][r];
        }
  } else if (b == 64) {
    f32x4 acc[4][4] = {};
    frag_gemm_acc_g<4, 8>(huf + 32 * 16384, 0, w1f, acc);
    float* pb = (float*)(ws + OFF_PB);
#pragma unroll
    for (int g = 0; g < 4; ++g)
#pragma unroll
      for (int f = 0; f < 4; ++f)
#pragma unroll
        for (int r = 0; r < 4; ++r) {
          int row = g * 16 + g16 * 4 + r;
          int col = cg * 64 + f * 16 + cl;
          pb[row * 256 + col] = acc[g][f][r] + msg_b1[col];
        }
  } else {
    const float* hb  = (const float*)(ws + OFF_HB);
    const float* wqa = (const float*)(ws + OFF_ATT);
    const float* c0  = wqa + 512;
    float* spr = (float*)(ws + OFF_SPR);
    const int t = threadIdx.x;
    if (t < 64) {
      float s = 0.f;
      for (int k = 0; k < 256; ++k) s += hb[t * 256 + k] * wqa[k];
      spr[t] = s + c0[0];
    }
  }
}

// =====================================================================
// K3: edge msg layer-2 + attention + chunk softmax.
// 16 waves (4rg x 4cg). ks-ROTATION (m+ch)&7 de-hotspots shared W2F/A
// L2 lines. Staging-time A repack (once), gl16 B dbuf, setprio on MFMA.
// =====================================================================
__global__ __launch_bounds__(1024, 2) void k3_edge(const float* __restrict__ msg_b2,
                                                   char* __restrict__ ws)
{
  const char*  PUBF = (const char*)(ws + OFF_PUBF);
  const float* PB   = (const float*)(ws + OFF_PB);
  const float* spr  = (const float*)(ws + OFF_SPR);
  const float* vv   = (const float*)(ws + OFF_ATT) + 256;
  const char*  W2F  = (const char*)(ws + OFF_W2F);
  float* crec = (float*)(ws + OFF_CREC);

  __shared__ __align__(16) char bufA[2][16384];
  __shared__ __align__(16) char bufB[2][16384];
  __shared__ float plds[16][64];
  __shared__ float redmax[16], wds[16];
  __shared__ float wvs[4][256];

  const int m = blockIdx.x >> 3, ch = blockIdx.x & 7;
  const int tid = threadIdx.x, wave = tid >> 6, lane = tid & 63;
  const int cl = lane & 15, g16 = lane >> 4;
  const int rg = wave >> 2, cg = wave & 3;
  const int rot = (m + ch) & 7;            // de-hotspot rotation
  const float sm = spr[m];
  const char* Asrc = PUBF + ch * 131072;
  const float* pbm = PB + m * 256;

  // prologue: stage tile rot (repack A in regs, gl16 B)
  {
    bf16x8 araw = *(const bf16x8*)(Asrc + rot * 16384 + wave * 1024 + lane * 16);
    gl16(W2F + rot * 16384 + wave * 1024 + lane * 16, &bufB[0][wave * 1024]);
    const float* pbp = pbm + rot * 32 + (lane >> 4) * 8;
    f32x4 p0 = *(const f32x4*)pbp, p1 = *(const f32x4*)(pbp + 4);
    bf16x8 a;
#pragma unroll
    for (int r = 0; r < 4; ++r) {
      a[r]     = (__bf16)fmaxf((float)araw[r]     + p0[r], 0.f);
      a[4 + r] = (__bf16)fmaxf((float)araw[4 + r] + p1[r], 0.f);
    }
    *(bf16x8*)(&bufA[0][wave * 1024 + lane * 16]) = a;
  }
  __syncthreads();

  f32x4 acc[4][4] = {};
  for (int i = 0; i < 8; ++i) {
    const int cur = i & 1;
    bf16x8 arn{};
    f32x4 pn0{}, pn1{};
    if (i < 7) {
      const int ksn = (i + 1 + rot) & 7;
      arn = *(const bf16x8*)(Asrc + ksn * 16384 + wave * 1024 + lane * 16);
      gl16(W2F + ksn * 16384 + wave * 1024 + lane * 16, &bufB[cur ^ 1][wave * 1024]);
      const float* pbp = pbm + ksn * 32 + (lane >> 4) * 8;
      pn0 = *(const f32x4*)pbp;
      pn1 = *(const f32x4*)(pbp + 4);
    }
    bf16x8 Af[4], Bf[4];
#pragma unroll
    for (int g = 0; g < 4; ++g)
      Af[g] = *(const bf16x8*)(&bufA[cur][((rg * 4 + g) * 64 + lane) * 16]);
#pragma unroll
    for (int f = 0; f < 4; ++f)
      Bf[f] = *(const bf16x8*)(&bufB[cur][((cg * 4 + f) * 64 + lane) * 16]);
    __builtin_amdgcn_s_setprio(1);
#pragma unroll
    for (int g = 0; g < 4; ++g)
#pragma unroll
      for (int f = 0; f < 4; ++f)
        acc[g][f] = __builtin_amdgcn_mfma_f32_16x16x32_bf16(Af[g], Bf[f], acc[g][f], 0, 0, 0);
    __builtin_amdgcn_s_setprio(0);
    if (i < 7) {
      bf16x8 a;
#pragma unroll
      for (int r = 0; r < 4; ++r) {
        a[r]     = (__bf16)fmaxf((float)arn[r]     + pn0[r], 0.f);
        a[4 + r] = (__bf16)fmaxf((float)arn[4 + r] + pn1[r], 0.f);
      }
      *(bf16x8*)(&bufA[cur ^ 1][wave * 1024 + lane * 16]) = a;
    }
    __syncthreads();
  }

  // msg = relu(acc + b2); logit partial over this wave's 64 cols
  float p[4][4] = {};
#pragma unroll
  for (int f = 0; f < 4; ++f) {
    const int j = cg * 64 + f * 16 + cl;
    const float b2j = msg_b2[j], vj = vv[j];
#pragma unroll
    for (int g = 0; g < 4; ++g)
#pragma unroll
      for (int r = 0; r < 4; ++r) {
        float mv = fmaxf(acc[g][f][r] + b2j, 0.f);
        acc[g][f][r] = mv;
        p[g][r] += mv * vj;
      }
  }
#pragma unroll
  for (int mask = 1; mask < 16; mask <<= 1)
#pragma unroll
    for (int g = 0; g < 4; ++g)
#pragma unroll
      for (int r = 0; r < 4; ++r) p[g][r] += __shfl_xor(p[g][r], mask);
  if (cl == 0) {
#pragma unroll
    for (int g = 0; g < 4; ++g)
#pragma unroll
      for (int r = 0; r < 4; ++r) plds[wave][g * 16 + g16 * 4 + r] = p[g][r];
  }
  __syncthreads();

  float lr[4][4], wm = -3.4e38f;
#pragma unroll
  for (int g = 0; g < 4; ++g)
#pragma unroll
    for (int r = 0; r < 4; ++r) {
      int row = g * 16 + g16 * 4 + r;
      float l = plds[rg * 4 + 0][row] + plds[rg * 4 + 1][row] +
                plds[rg * 4 + 2][row] + plds[rg * 4 + 3][row] + sm;
      l = l > 0.f ? l : 0.2f * l;
      lr[g][r] = l;
      wm = fmaxf(wm, l);
    }
  wm = fmaxf(wm, __shfl_xor(wm, 16));
  wm = fmaxf(wm, __shfl_xor(wm, 32));
  if (lane == 0) redmax[wave] = wm;
  __syncthreads();
  float Mc = redmax[0];
#pragma unroll
  for (int i = 1; i < 16; ++i) Mc = fmaxf(Mc, redmax[i]);

  float e[4][4], ds = 0.f;
#pragma unroll
  for (int g = 0; g < 4; ++g)
#pragma unroll
    for (int r = 0; r < 4; ++r) { e[g][r] = __expf(lr[g][r] - Mc); ds += e[g][r]; }
  ds += __shfl_xor(ds, 16);
  ds += __shfl_xor(ds, 32);
  if (lane == 0) wds[wave] = ds;

#pragma unroll
  for (int f = 0; f < 4; ++f) {
    float w = 0.f;
#pragma unroll
    for (int g = 0; g < 4; ++g)
#pragma unroll
      for (int r = 0; r < 4; ++r) w += e[g][r] * acc[g][f][r];
    w += __shfl_xor(w, 16);
    w += __shfl_xor(w, 32);
    if (g16 == 0) wvs[rg][cg * 64 + f * 16 + cl] = w;
  }
  __syncthreads();

  float* rec = crec + (m * 8 + ch) * 260;
  if (tid < 256) rec[tid] = wvs[0][tid] + wvs[1][tid] + wvs[2][tid] + wvs[3][tid];
  if (tid == 0) rec[256] = Mc;
  if (tid == 1) rec[257] = wds[0] + wds[4] + wds[8] + wds[12];
}

// =====================================================================
// K56: fused update MLP + user lin2+sigmoid. 66 blocks of 32 rows:
// b<64 users (h-half layer1); b=64,65: 32 UAVs each (agg combine + full).
// =====================================================================
__global__ __launch_bounds__(256) void k56_update(
    const float* __restrict__ upd_b1, const float* __restrict__ upd_b2,
    const float* __restrict__ lin2_w, const float* __restrict__ lin2_b,
    float* __restrict__ out, char* __restrict__ ws)
{
  const __bf16* huf  = (const __bf16*)(ws + OFF_HUF);
  const __bf16* uw1f = (const __bf16*)(ws + OFF_UW1F);
  const __bf16* uw2f = (const __bf16*)(ws + OFF_UW2F);

  __shared__ __align__(16) __bf16 l1f[8 * 2 * 512];   // 16 KB layer1 frag (32 rows)
  __shared__ __align__(16) __bf16 aggf[8 * 2 * 512];  // 16 KB agg frag (32 uav rows)
  __shared__ float scs[32][8];
  __shared__ float sS[32];
  __shared__ float l2p[4][32][2];

  const int b = blockIdx.x, tid = threadIdx.x;
  const int lane = tid & 63, cg = tid >> 6;
  const int cl = lane & 15, g16 = lane >> 4;

  f32x4 acc[2][4] = {};
  if (b < 64) {
    frag_gemm_acc_g<2, 8>(huf + (b >> 1) * 16384, (b & 1) * 2, uw1f + 8 * 16 * 512, acc);
  } else {
    const int m0 = (b - 64) * 32;
    const float* crec = (const float*)(ws + OFF_CREC);
    if (tid < 32) {
      const int m = m0 + tid;
      float mx = -3.4e38f;
      for (int c = 0; c < 8; ++c) mx = fmaxf(mx, crec[(m * 8 + c) * 260 + 256]);
      float S = 0.f;
      for (int c = 0; c < 8; ++c) {
        float sc = __expf(crec[(m * 8 + c) * 260 + 256] - mx);
        scs[tid][c] = sc;
        S += sc * crec[(m * 8 + c) * 260 + 257];
      }
      sS[tid] = S;
    }
    __syncthreads();
    for (int ml = 0; ml < 32; ++ml) {
      float A = 0.f;
#pragma unroll
      for (int c = 0; c < 8; ++c) A += scs[ml][c] * crec[((m0 + ml) * 8 + c) * 260 + tid];
      float agg = A / sS[ml] * (1.f / 2048.f);
      aggf[((tid >> 5) * 2 + (ml >> 4)) * 512 + (((tid >> 3) & 3) * 16 + (ml & 15)) * 8 + (tid & 7)] =
          (__bf16)agg;
    }
    __syncthreads();
    const int g0 = (b - 64) * 2;
    const __bf16* hufu = huf + 32 * 16384;
    for (int ks = 0; ks < 8; ++ks) {
      bf16x8 Af[2], Bf[4];
#pragma unroll
      for (int g = 0; g < 2; ++g)
        Af[g] = *(const bf16x8*)(aggf + ((ks * 2 + g) * 64 + lane) * 8);
#pragma unroll
      for (int f = 0; f < 4; ++f)
        Bf[f] = *(const bf16x8*)(uw1f + ((ks * 16 + cg * 4 + f) * 64 + lane) * 8);
#pragma unroll
      for (int g = 0; g < 2; ++g)
#pragma unroll
        for (int f = 0; f < 4; ++f)
          acc[g][f] = __builtin_amdgcn_mfma_f32_16x16x32_bf16(Af[g], Bf[f], acc[g][f], 0, 0, 0);
    }
    for (int ks = 8; ks < 16; ++ks) {
      bf16x8 Af[2], Bf[4];
#pragma unroll
      for (int g = 0; g < 2; ++g)
        Af[g] = *(const bf16x8*)(hufu + (((ks - 8) * 4 + g0 + g) * 64 + lane) * 8);
#pragma unroll
      for (int f = 0; f < 4; ++f)
        Bf[f] = *(const bf16x8*)(uw1f + ((ks * 16 + cg * 4 + f) * 64 + lane) * 8);
#pragma unroll
      for (int g = 0; g < 2; ++g)
#pragma unroll
        for (int f = 0; f < 4; ++f)
          acc[g][f] = __builtin_amdgcn_mfma_f32_16x16x32_bf16(Af[g], Bf[f], acc[g][f], 0, 0, 0);
    }
  }

  // bias + relu -> l1f (32-row frag-major in LDS)
#pragma unroll
  for (int g = 0; g < 2; ++g)
#pragma unroll
    for (int f = 0; f < 4; ++f) {
      const int col = cg * 64 + f * 16 + cl;
      const float b1 = upd_b1[col];
#pragma unroll
      for (int r = 0; r < 4; ++r) {
        float v = fmaxf(acc[g][f][r] + b1, 0.f);
        l1f[((col >> 5) * 2 + g) * 512 + (((col >> 3) & 3) * 16 + g16 * 4 + r) * 8 + (col & 7)] =
            (__bf16)v;
      }
    }
  __syncthreads();

  // layer2
  f32x4 a2[2][4] = {};
  for (int ks = 0; ks < 8; ++ks) {
    bf16x8 Af[2], Bf[4];
#pragma unroll
    for (int g = 0; g < 2; ++g)
      Af[g] = *(const bf16x8*)(l1f + ((ks * 2 + g) * 64 + lane) * 8);
#pragma unroll
    for (int f = 0; f < 4; ++f)
      Bf[f] = *(const bf16x8*)(uw2f + ((ks * 16 + cg * 4 + f) * 64 + lane) * 8);
#pragma unroll
    for (int g = 0; g < 2; ++g)
#pragma unroll
      for (int f = 0; f < 4; ++f)
        a2[g][f] = __builtin_amdgcn_mfma_f32_16x16x32_bf16(Af[g], Bf[f], a2[g][f], 0, 0, 0);
  }

  if (b < 64) {
    float d0[2][4] = {}, d1[2][4] = {};
#pragma unroll
    for (int f = 0; f < 4; ++f) {
      const int col = cg * 64 + f * 16 + cl;
      const float b2 = upd_b2[col];
      const float w0 = lin2_w[col], w1 = lin2_w[256 + col];
#pragma unroll
      for (int g = 0; g < 2; ++g)
#pragma unroll
        for (int r = 0; r < 4; ++r) {
          float hv = fmaxf(a2[g][f][r] + b2, 0.f);
          d0[g][r] += hv * w0;
          d1[g][r] += hv * w1;
        }
    }
#pragma unroll
    for (int mask = 1; mask < 16; mask <<= 1)
#pragma unroll
      for (int g = 0; g < 2; ++g)
#pragma unroll
        for (int r = 0; r < 4; ++r) {
          d0[g][r] += __shfl_xor(d0[g][r], mask);
          d1[g][r] += __shfl_xor(d1[g][r], mask);
        }
    if (cl == 0) {
#pragma unroll
      for (int g = 0; g < 2; ++g)
#pragma unroll
        for (int r = 0; r < 4; ++r) {
          l2p[cg][g * 16 + g16 * 4 + r][0] = d0[g][r];
          l2p[cg][g * 16 + g16 * 4 + r][1] = d1[g][r];
        }
    }
    __syncthreads();
    if (tid < 32) {
      float s0 = l2p[0][tid][0] + l2p[1][tid][0] + l2p[2][tid][0] + l2p[3][tid][0] + lin2_b[0];
      float s1 = l2p[0][tid][1] + l2p[1][tid][1] + l2p[2][tid][1] + l2p[3][tid][1] + lin2_b[1];
      const int row = b * 32 + tid;
      out[row * 2 + 0] = 1.f / (1.f + expf(-s0));
      out[row * 2 + 1] = 1.f / (1.f + expf(-s1));
    }
  } else {
    float* h2u = (float*)(ws + OFF_H2U);
    const int m0 = (b - 64) * 32;
#pragma unroll
    for (int g = 0; g < 2; ++g)
#pragma unroll
      for (int f = 0; f < 4; ++f) {
        const int col = cg * 64 + f * 16 + cl;
        const float b2 = upd_b2[col];
#pragma unroll
        for (int r = 0; r < 4; ++r) {
          const int rl = g * 16 + g16 * 4 + r;
          h2u[(m0 + rl) * 256 + col] = fmaxf(a2[g][f][r] + b2, 0.f);
        }
      }
  }
}

// =====================================================================
// K7a: UAV LSTM gate partials, k-quartered. grid 256 = 64 m x 4 kq.
// =====================================================================
__global__ __launch_bounds__(256) void k7a_gates(char* __restrict__ ws)
{
  const float* h2u  = (const float*)(ws + OFF_H2U);
  const float* wihT = (const float*)(ws + OFF_WIHT);
  float* part = (float*)(ws + OFF_PART);
  const int m = blockIdx.x >> 2, kq = blockIdx.x & 3;
  const int tid = threadIdx.x;
  const int dir = tid >> 7, hc = tid & 127;
  __shared__ float xs[64];
  if (tid < 64) xs[tid] = h2u[m * 256 + kq * 64 + tid];
  __syncthreads();
  f32x4 a4 = {0.f, 0.f, 0.f, 0.f};
  for (int k = 0; k < 64; ++k) {
    float xv = xs[k];
    f32x4 wv4 = *(const f32x4*)(wihT + dir * 131072 + (kq * 64 + k) * 512 + hc * 4);
#pragma unroll
    for (int g = 0; g < 4; ++g) a4[g] += xv * wv4[g];
  }
  *(f32x4*)(part + (m * 4 + kq) * 1024 + dir * 512 + hc * 4) = a4;
}

// =====================================================================
// K7b: combine partials + LSTM nonlinearity + lin2 + sigmoid (64 blocks)
// =====================================================================
__global__ __launch_bounds__(256) void k7b_final(
    const float* __restrict__ uavl_b, const float* __restrict__ lin2_w,
    const float* __restrict__ lin2_b, float* __restrict__ out, char* __restrict__ ws)
{
  const float* part = (const float*)(ws + OFF_PART);
  const int m = blockIdx.x, tid = threadIdx.x;
  const int dir = tid >> 7, hc = tid & 127;
  f32x4 a4 = {0.f, 0.f, 0.f, 0.f};
#pragma unroll
  for (int kq = 0; kq < 4; ++kq) {
    f32x4 p = *(const f32x4*)(part + (m * 4 + kq) * 1024 + dir * 512 + hc * 4);
#pragma unroll
    for (int g = 0; g < 4; ++g) a4[g] += p[g];
  }
  float bb[4];
#pragma unroll
  for (int g = 0; g < 4; ++g) bb[g] = uavl_b[dir * 512 + g * 128 + hc];
  __shared__ float uo[256];
  float ii = sigm(a4[0] + bb[0]);
  float gg = tanhf(a4[2] + bb[2]);
  float oo = sigm(a4[3] + bb[3]);
  float cc = ii * gg;
  uo[dir * 128 + hc] = oo * tanhf(cc);
  __syncthreads();
  float p0 = uo[tid] * lin2_w[tid];
  float p1 = uo[tid] * lin2_w[256 + tid];
#pragma unroll
  for (int mask = 1; mask < 64; mask <<= 1) {
    p0 += __shfl_xor(p0, mask);
    p1 += __shfl_xor(p1, mask);
  }
  __shared__ float r0s[4], r1s[4];
  const int lane = tid & 63, wv = tid >> 6;
  if (lane == 0) { r0s[wv] = p0; r1s[wv] = p1; }
  __syncthreads();
  if (tid == 0) {
    float d0 = r0s[0] + r0s[1] + r0s[2] + r0s[3] + lin2_b[0];
    float d1 = r1s[0] + r1s[1] + r1s[2] + r1s[3] + lin2_b[1];
    out[(NUQ + m) * 2 + 0] = 1.f / (1.f + expf(-d0));
    out[(NUQ + m) * 2 + 1] = 1.f / (1.f + expf(-d1));
  }
}

// =====================================================================
extern "C" void kernel_launch(void* const* d_in, const int* in_sizes, int n_in,
                              void* d_out, int out_size, void* d_ws, size_t ws_size,
                              hipStream_t stream)
{
  const float* x         = (const float*)d_in[0];
  const float* ul_wih    = (const float*)d_in[3];
  const float* ul_whh    = (const float*)d_in[4];
  const float* ul_b      = (const float*)d_in[5];
  const float* uav_lin_w = (const float*)d_in[6];
  const float* uav_lin_b = (const float*)d_in[7];
  const float* msg_w1    = (const float*)d_in[8];
  const float* msg_b1    = (const float*)d_in[9];
  const float* msg_w2    = (const float*)d_in[10];
  const float* msg_b2    = (const float*)d_in[11];
  const float* wq_w      = (const float*)d_in[12];
  const float* wq_b      = (const float*)d_in[13];
  const float* wr_w      = (const float*)d_in[14];
  const float* wr_b      = (const float*)d_in[15];
  const float* att_w     = (const float*)d_in[16];
  const float* att_b     = (const float*)d_in[17];
  const float* upd_w1    = (const float*)d_in[18];
  const float* upd_b1    = (const float*)d_in[19];
  const float* upd_w2    = (const float*)d_in[20];
  const float* upd_b2    = (const float*)d_in[21];
  const float* uavl_wih  = (const float*)d_in[22];
  const float* uavl_b    = (const float*)d_in[24];
  const float* lin2_w    = (const float*)d_in[25];
  const float* lin2_b    = (const float*)d_in[26];
  char* ws = (char*)d_ws;
  float* out = (float*)d_out;

  k0_prep<<<dim3(161), dim3(256), 0, stream>>>(ul_whh, uavl_wih, msg_w1, msg_w2, upd_w1,
                                               upd_w2, att_w, att_b, wq_w, wq_b, wr_w, wr_b, ws);
  k1_embed<<<dim3(260), dim3(256), 0, stream>>>(x, ul_wih, ul_b, uav_lin_w, uav_lin_b, ws);
  k2_proj<<<dim3(66), dim3(256), 0, stream>>>(msg_b1, ws);
  k3_edge<<<dim3(512), dim3(1024), 0, stream>>>(msg_b2, ws);
  k56_update<<<dim3(66), dim3(256), 0, stream>>>(upd_b1, upd_b2, lin2_w, lin2_b, out, ws);
  k7a_gates<<<dim3(256), dim3(256), 0, stream>>>(ws);
  k7b_final<<<dim3(64), dim3(256), 0, stream>>>(uavl_b, lin2_w, lin2_b, out, ws);
}